// Round 18
// baseline (743.251 us; speedup 1.0000x reference)
//
#include <hip/hip_runtime.h>
#include <hip/hip_bf16.h>

#define DEV __device__ __forceinline__

typedef __attribute__((ext_vector_type(8))) short short8;
typedef __attribute__((ext_vector_type(4))) float f32x4;

DEV unsigned short f2b(float f) {
  union { float f; unsigned u; } v; v.f = f;
  unsigned r = v.u + 0x7FFFu + ((v.u >> 16) & 1u);  // RNE
  return (unsigned short)(r >> 16);
}
DEV float b2f16(unsigned short b) {
  union { unsigned u; float f; } v; v.u = ((unsigned)b) << 16;
  return v.f;
}
// cheap truncation split: hi+lo carry ~16 mantissa bits (error ~2^-17 rel)
DEV void tsplit(float v, short& h, short& l) {
  union { float f; unsigned u; } c; c.f = v;
  unsigned short hu = (unsigned short)(c.u >> 16);
  union { unsigned u; float f; } hb; hb.u = (unsigned)hu << 16;
  union { float f; unsigned u; } c2; c2.f = v - hb.f;
  h = (short)hu; l = (short)(c2.u >> 16);
}

// ---------------- fused weight cast f32 -> bf16 hi/lo arenas (RNE, one-time) ----------------
// conv weights are stored TAP-MAJOR: dst[co*864 + k9*96 + ci] = src[co*864 + ci*9 + k9]
__global__ void k_castw(const float* __restrict__ s0, const float* __restrict__ s1,
    const float* __restrict__ s2, const float* __restrict__ s3,
    const float* __restrict__ s4, const float* __restrict__ s5,
    const float* __restrict__ s6, const float* __restrict__ s7,
    const float* __restrict__ s8, const float* __restrict__ s9,
    short* __restrict__ dh, short* __restrict__ dl) {
  int idx = blockIdx.x * 256 + threadIdx.x;
  if (idx >= 1096704) return;
  float v;
  if (idx < 165888) {
    int co = idx / 864, rem = idx % 864;
    int k9 = rem / 96, ci = rem % 96;
    v = s0[co * 864 + ci * 9 + k9];
  } else {
    const float* src; int base;
    if      (idx < 175104) { src = s1; base = 165888; }
    else if (idx < 193536) { src = s2; base = 175104; }
    else if (idx < 211968) { src = s3; base = 193536; }
    else if (idx < 285696) { src = s4; base = 211968; }
    else if (idx < 359424) { src = s5; base = 285696; }
    else if (idx < 580608) { src = s6; base = 359424; }
    else if (idx < 654336) { src = s7; base = 580608; }
    else if (idx < 875520) { src = s8; base = 654336; }
    else                   { src = s9; base = 875520; }
    v = src[idx - base];
  }
  unsigned short h = f2b(v);
  dh[idx] = (short)h;
  dl[idx] = (short)f2b(v - b2f16(h));
}

// ---------------- rope tables: ct/st [784][16] ----------------
__global__ void k_rope(float* ct, float* st) {
  int idx = blockIdx.x * 256 + threadIdx.x;
  if (idx >= 784 * 16) return;
  int n = idx >> 4, j = idx & 15;
  float inv = powf(10000.f, -(float)(2 * j) / 32.f);
  float ang = (float)n * inv;
  ct[idx] = cosf(ang);
  st[idx] = sinf(ang);
}

// ---------------- LN row stats: (mean, rstd) per row ----------------
template<int D>
__global__ __launch_bounds__(256) void k_lnstat(const float* __restrict__ in,
    float2* __restrict__ stats, int M) {
  int tok = blockIdx.x * 4 + (threadIdx.x >> 6);
  int l = threadIdx.x & 63;
  if (tok >= M) return;  // wave-uniform
  const float* row = in + (size_t)tok * D;
  constexpr int E = (D + 63) / 64;
  float s = 0.f, s2 = 0.f;
#pragma unroll
  for (int e = 0; e < E; ++e) {
    int i = e * 64 + l;
    float x = (i < D) ? row[i] : 0.f;
    s += x; s2 += x * x;
  }
  for (int off = 32; off; off >>= 1) { s += __shfl_xor(s, off); s2 += __shfl_xor(s2, off); }
  float mean = s / D, var = s2 / D - mean * mean;
  if (l == 0) stats[tok] = make_float2(mean, rsqrtf(var + 1e-5f));
}

// ---------------- LN epilogue over D=192: out = (write|add) LN(raw); emits row stats ----------------
template<int ADD>
__global__ __launch_bounds__(256) void k_ln_epi(const float* __restrict__ raw,
    const float* __restrict__ g, const float* __restrict__ b,
    float* __restrict__ out, float2* __restrict__ stats, int M) {
  int tok = blockIdx.x * 4 + (threadIdx.x >> 6);
  int l = threadIdx.x & 63;
  if (tok >= M) return;
  const float* row = raw + (size_t)tok * 192;
  float v[3];
  float s = 0.f, s2 = 0.f;
#pragma unroll
  for (int e = 0; e < 3; ++e) {
    float x = row[e * 64 + l];
    v[e] = x; s += x; s2 += x * x;
  }
  for (int off = 32; off; off >>= 1) { s += __shfl_xor(s, off); s2 += __shfl_xor(s2, off); }
  float mean = s / 192.f, var = s2 / 192.f - mean * mean;
  float rstd = rsqrtf(var + 1e-5f);
  float* orow = out + (size_t)tok * 192;
  float t = 0.f, t2 = 0.f;
#pragma unroll
  for (int e = 0; e < 3; ++e) {
    int i = e * 64 + l;
    float r = (v[e] - mean) * rstd * g[i] + b[i];
    float nv = ADD ? (orow[i] + r) : r;
    orow[i] = nv;
    t += nv; t2 += nv * nv;
  }
  for (int off = 32; off; off >>= 1) { t += __shfl_xor(t, off); t2 += __shfl_xor(t2, off); }
  float m2 = t / 192.f, v2 = t2 / 192.f - m2 * m2;
  if (l == 0) stats[tok] = make_float2(m2, rsqrtf(v2 + 1e-5f));
}

// ---------------- MFMA bf16x2 split GEMM: C = (LN?)(A) @ W^T ----------------
// tile 32(M) x 64(N), BK=32, 128 threads = 2 waves; wave w owns N-half (32 cols),
// 2x2 16x16 frags per wave. acc = ah*bh + ah*bl + al*bh.
// EPI: 0 store | 1 gelu+store | 2 add-into-C | 3 rope-scatter to o1/o2/o3 (qkv).
// CONV: im2col, weights TAP-MAJOR. LNS: apply LN to A rows using precomputed stats.
template<int EPI, int CONV, int LNS>
__global__ __launch_bounds__(128) void k_mgemm(
    const float* __restrict__ A, const short* __restrict__ WH,
    const short* __restrict__ WL, const float* __restrict__ bias,
    float* __restrict__ C, int M, int N, int K,
    const float2* __restrict__ lnstats, const float* __restrict__ lng,
    const float* __restrict__ lnb,
    const float* __restrict__ ct, const float* __restrict__ st,
    float* __restrict__ o1, float* __restrict__ o2, float* __restrict__ o3) {
  __shared__ short AsH[32][40], AsL[32][40];
  __shared__ short BsH[64][40], BsL[64][40];
  int t = threadIdx.x;
  int m0 = blockIdx.x * 32, n0 = blockIdx.y * 64;
  int sr = t >> 2, sq = (t & 3) * 8;       // A stage: row [0,32), k-offset (8/thread)
  int sr2 = t >> 1, sq2 = (t & 1) * 16;    // B stage: row [0,64), k-half (16/thread)
  int lane = t & 63, w = t >> 6;           // wave w in {0,1} -> N-half
  int fr = lane & 15, fq = lane >> 4;      // frag row, k-block
  float2 lst = make_float2(0.f, 1.f);
  if (LNS) lst = lnstats[m0 + sr];
  f32x4 acc[2][2];
#pragma unroll
  for (int i = 0; i < 2; ++i)
#pragma unroll
    for (int j = 0; j < 2; ++j) acc[i][j] = (f32x4){0.f, 0.f, 0.f, 0.f};

  for (int kt = 0; kt < K; kt += 32) {
    // ---- A tile: 32 rows x 32 k -> hi/lo bf16 (truncation split), 16B LDS writes ----
    short8 vh, vl;
    if (CONV) {
      int m = m0 + sr;
      int b = m / 784, rm = m % 784, ho = rm / 28, wo = rm % 28;
      int k = kt + sq;                      // octet never straddles a tap (96 % 8 == 0)
      int k9 = k / 96, ci0 = k % 96;
      int hi = 2 * ho - 1 + k9 / 3, wi = 2 * wo - 1 + k9 % 3;
      if (hi >= 0 && hi < 56 && wi >= 0 && wi < 56) {
        const float* src = &A[((size_t)b * 3136 + hi * 56 + wi) * 96 + ci0];
        float4 a0 = *(const float4*)src;
        float4 a1 = *(const float4*)(src + 4);
        float av[8] = {a0.x, a0.y, a0.z, a0.w, a1.x, a1.y, a1.z, a1.w};
#pragma unroll
        for (int j = 0; j < 8; ++j) { short h, l2; tsplit(av[j], h, l2); vh[j] = h; vl[j] = l2; }
      } else {
#pragma unroll
        for (int j = 0; j < 8; ++j) { vh[j] = 0; vl[j] = 0; }
      }
    } else {
      const float4 a0 = *(const float4*)&A[(size_t)(m0 + sr) * K + kt + sq];
      const float4 a1 = *(const float4*)&A[(size_t)(m0 + sr) * K + kt + sq + 4];
      float av[8] = {a0.x, a0.y, a0.z, a0.w, a1.x, a1.y, a1.z, a1.w};
#pragma unroll
      for (int j = 0; j < 8; ++j) {
        if (LNS) av[j] = (av[j] - lst.x) * lst.y * lng[kt + sq + j] + lnb[kt + sq + j];
        short h, l2; tsplit(av[j], h, l2); vh[j] = h; vl[j] = l2;
      }
    }
    *(short8*)&AsH[sr][sq] = vh;
    *(short8*)&AsL[sr][sq] = vl;
    // ---- B tile: row sr2, k-half sq2 (two short8 loads) ----
    {
      int n = n0 + sr2;
      if (n < N) {
        *(short8*)&BsH[sr2][sq2]     = *(const short8*)&WH[(size_t)n * K + kt + sq2];
        *(short8*)&BsH[sr2][sq2 + 8] = *(const short8*)&WH[(size_t)n * K + kt + sq2 + 8];
        *(short8*)&BsL[sr2][sq2]     = *(const short8*)&WL[(size_t)n * K + kt + sq2];
        *(short8*)&BsL[sr2][sq2 + 8] = *(const short8*)&WL[(size_t)n * K + kt + sq2 + 8];
      } else {
        short8 z = {0, 0, 0, 0, 0, 0, 0, 0};
        *(short8*)&BsH[sr2][sq2] = z; *(short8*)&BsH[sr2][sq2 + 8] = z;
        *(short8*)&BsL[sr2][sq2] = z; *(short8*)&BsL[sr2][sq2 + 8] = z;
      }
    }
    __syncthreads();
    short8 ah[2], al[2], bh[2], bl[2];
#pragma unroll
    for (int s = 0; s < 2; ++s) {
      ah[s] = *(const short8*)&AsH[s * 16 + fr][fq * 8];
      al[s] = *(const short8*)&AsL[s * 16 + fr][fq * 8];
      bh[s] = *(const short8*)&BsH[w * 32 + s * 16 + fr][fq * 8];
      bl[s] = *(const short8*)&BsL[w * 32 + s * 16 + fr][fq * 8];
    }
#pragma unroll
    for (int i = 0; i < 2; ++i)
#pragma unroll
      for (int j = 0; j < 2; ++j) {
        acc[i][j] = __builtin_amdgcn_mfma_f32_16x16x32_bf16(ah[i], bh[j], acc[i][j], 0, 0, 0);
        acc[i][j] = __builtin_amdgcn_mfma_f32_16x16x32_bf16(ah[i], bl[j], acc[i][j], 0, 0, 0);
        acc[i][j] = __builtin_amdgcn_mfma_f32_16x16x32_bf16(al[i], bh[j], acc[i][j], 0, 0, 0);
      }
    __syncthreads();
  }
  // epilogue: C/D layout col = lane&15, row = (lane>>4)*4 + r   [m89]
#pragma unroll
  for (int i = 0; i < 2; ++i) {
#pragma unroll
    for (int j = 0; j < 2; ++j) {
      int n = n0 + w * 32 + j * 16 + fr;
#pragma unroll
      for (int r = 0; r < 4; ++r) {
        int m = m0 + i * 16 + fq * 4 + r;
        float v = acc[i][j][r];
        float pa = 0.f;
        if (EPI == 3) pa = __shfl_xor(v, 1);  // rope partner (n^1 <-> lane^1); all lanes
        if (n >= N) continue;
        if (bias) v += bias[n];
        if (EPI == 1) v = 0.5f * v * (1.f + erff(v * 0.70710678118654752f));
        if (EPI == 3) {
          int sec = n / 192, d = n % 192, h = d / 32, dh = d % 32;
          int b = m / 784, mm = m % 784;
          float val;
          if (sec < 2) {
            int jj = dh >> 1;
            float cc = ct[mm * 16 + jj], ss = st[mm * 16 + jj];
            val = (dh & 1) ? (v * cc + pa * ss) : (v * cc - pa * ss);
          } else val = v;
          float* dst = (sec == 0) ? o1 : ((sec == 1) ? o2 : o3);
          dst[(((size_t)b * 6 + h) * 784 + mm) * 32 + dh] = val;
        } else if (EPI == 2) {
          C[(size_t)m * N + n] += v;
        } else {
          C[(size_t)m * N + n] = v;
        }
      }
    }
  }
}

// ---------------- pass1: wave-per-token softmax stats over deduped <=9 neighbors ----------------
__global__ __launch_bounds__(256) void k_pass1(const float* __restrict__ kk,
    const float* __restrict__ q, const float* __restrict__ rpb,
    const float* __restrict__ tau, float* __restrict__ M, float* __restrict__ Z) {
  int tok = blockIdx.x * 4 + (threadIdx.x >> 6);   // [0, 25088)
  int l = threadIdx.x & 63;
  int b = tok / 3136, n = tok % 3136;
  int r = n / 56, c = n % 56, r0 = r >> 1, c0 = c >> 1;
  int oi[9]; bool keep[9];
#pragma unroll
  for (int kki = 0; kki < 9; ++kki) {
    int dr = kki / 3 - 1, dc = kki % 3 - 1;
    int rr = min(max(r0 + dr, 0), 27), cc = min(max(c0 + dc, 0), 27);
    oi[kki] = rr * 28 + cc;
  }
#pragma unroll
  for (int kki = 0; kki < 9; ++kki) {
    bool kp = true;
#pragma unroll
    for (int k2 = kki + 1; k2 < 9; ++k2) if (oi[k2] == oi[kki]) kp = false;
    keep[kki] = kp;
  }
  float scale = expf(tau[0]);
  const float* kr = kk + (size_t)tok * 96;
  float k0 = kr[l];
  float k1 = (l < 32) ? kr[64 + l] : 0.f;
  float lg[9];
  float mx = -1e30f;
#pragma unroll
  for (int kki = 0; kki < 9; ++kki) {
    if (keep[kki]) {
      const float* qr = q + ((size_t)b * 784 + oi[kki]) * 96;
      float part = k0 * qr[l];
      if (l < 32) part += k1 * qr[64 + l];
      for (int off = 32; off; off >>= 1) part += __shfl_xor(part, off);
      lg[kki] = part * scale + rpb[kki];
      mx = fmaxf(mx, lg[kki]);
    } else lg[kki] = -1e30f;
  }
  float z = 0.f;
#pragma unroll
  for (int kki = 0; kki < 9; ++kki) if (keep[kki]) z += expf(lg[kki] - mx);
  if (l == 0) { M[tok] = mx; Z[tok] = z; }
}

// ---------------- pass2: wave-parallel p-compute, gather, /denom, LN, residual ----------------
// 256 threads = 4 waves; wave w computes p for neighbors jn = w, w+4, ...
// Dots computed exactly like pass1 (bit-identical logits).
__global__ __launch_bounds__(256) void k_pass2(const float* __restrict__ kk,
    const float* __restrict__ q, const float* __restrict__ vv,
    const float* __restrict__ M, const float* __restrict__ Z,
    const float* __restrict__ rpb, const float* __restrict__ tau,
    const float* __restrict__ g, const float* __restrict__ bb, float* __restrict__ xout) {
  int blk = blockIdx.x, b = blk / 784, m = blk % 784;
  int r2 = m / 28, c2 = m % 28;
  int r0lo = (r2 == 0) ? 0 : r2 - 1, r0hi = (r2 == 27) ? 27 : r2 + 1;
  int c0lo = (c2 == 0) ? 0 : c2 - 1, c0hi = (c2 == 27) ? 27 : c2 + 1;
  int nrow = 2 * (r0hi - r0lo + 1), ncol = 2 * (c0hi - c0lo + 1);
  int cnt = nrow * ncol;  // <= 36
  __shared__ float qm[96], p[36];
  __shared__ int nlist[36];
  __shared__ float2 red[192];
  int t = threadIdx.x, w = t >> 6, l = t & 63;
  if (t < 96) qm[t] = q[(size_t)blk * 96 + t];
  __syncthreads();
  float scale = expf(tau[0]);
  float q0 = qm[l];
  float q1 = (l < 32) ? qm[64 + l] : 0.f;
  for (int jn = w; jn < cnt; jn += 4) {
    int rr = 2 * r0lo + jn / ncol, cc = 2 * c0lo + jn % ncol;
    int n = rr * 56 + cc, rr0 = rr >> 1, cc0 = cc >> 1;
    int kkf = 0;
#pragma unroll
    for (int kki = 0; kki < 9; ++kki) {
      int dr = kki / 3 - 1, dc = kki % 3 - 1;
      int ra = min(max(rr0 + dr, 0), 27), ca = min(max(cc0 + dc, 0), 27);
      if (ra == r2 && ca == c2) kkf = kki;  // last-kk-wins (matches numpy overwrite)
    }
    const float* krow = kk + ((size_t)b * 3136 + n) * 96;
    float part = krow[l] * q0;
    if (l < 32) part += krow[64 + l] * q1;
    for (int off = 32; off; off >>= 1) part += __shfl_xor(part, off);
    if (l == 0) {
      float lg = part * scale + rpb[kkf];
      size_t idn = (size_t)b * 3136 + n;
      p[jn] = expf(lg - M[idn]) / Z[idn];
      nlist[jn] = n;
    }
  }
  __syncthreads();
  float upd = 0.f;
  if (t < 192) {
    float denom = 0.f;
    for (int jn = 0; jn < cnt; ++jn) denom += p[jn];
    float acc = 0.f;
    for (int jn = 0; jn < cnt; ++jn)
      acc += p[jn] * vv[((size_t)b * 3136 + nlist[jn]) * 192 + t];
    upd = acc / (denom + 1e-8f);
    red[t] = make_float2(upd, upd * upd);
  }
  __syncthreads();
  for (int s = 128; s > 0; s >>= 1) {
    if (t < s && t + s < 192) { red[t].x += red[t + s].x; red[t].y += red[t + s].y; }
    __syncthreads();
  }
  if (t < 192) {
    float mean = red[0].x / 192.f, var = red[0].y / 192.f - mean * mean;
    float rstd = rsqrtf(var + 1e-5f);
    xout[(size_t)blk * 192 + t] += (upd - mean) * rstd * g[t] + bb[t];
  }
}

// ---------------- neighborhood attention 7x7: literal-readlane pair-PV, dual acc ----------------
__global__ __launch_bounds__(256) void k_attn(const float* __restrict__ q3,
    const float* __restrict__ k3, const float* __restrict__ v3, float* __restrict__ ob) {
  int bid = blockIdx.x;
  int swz = (bid & 7) * 1176 + (bid >> 3);  // bijective on [0,9408)
  int unit = swz * 4 + (threadIdx.x >> 6);
  int l = threadIdx.x & 63;
  int b = unit / (6 * 784), rem = unit % (6 * 784), h = rem / 784, m = rem % 784;
  int i = m / 28, j = m % 28;
  int ib = min(max(i, 3), 24) - 3, jb = min(max(j, 3), 24) - 3;
  size_t base = (size_t)(b * 6 + h) * 784 * 32;
  const float4* q4 = (const float4*)(q3 + base + (size_t)m * 32);
  float4 qv[8];
#pragma unroll
  for (int e = 0; e < 8; ++e) qv[e] = q4[e];
  float logit = -1e30f;
  if (l < 49) {
    int nk = (ib + l / 7) * 28 + (jb + l % 7);
    const float4* k4 = (const float4*)(k3 + base + (size_t)nk * 32);
    float a = 0.f;
#pragma unroll
    for (int e = 0; e < 8; ++e) {
      float4 kv = k4[e];
      a += qv[e].x * kv.x + qv[e].y * kv.y + qv[e].z * kv.z + qv[e].w * kv.w;
    }
    logit = a * 0.17677669529663687f;  // 32^-0.5
  }
  float mx = logit;
  for (int off = 32; off; off >>= 1) mx = fmaxf(mx, __shfl_xor(mx, off));
  float p = (l < 49) ? expf(logit - mx) : 0.f;
  float sum = p;
  for (int off = 32; off; off >>= 1) sum += __shfl_xor(sum, off);
  int half = l >> 5, d = l & 31;
  const float* vb = v3 + base + d;
  int rowbase = ib * 28 + jb;
  float accA = 0.f, accB = 0.f;
  int pbits = __float_as_int(p);
#pragma unroll
  for (int kk2 = 0; kk2 < 25; ++kk2) {
    const int k0c = kk2;
    const int k1c = (kk2 + 25 <= 48) ? kk2 + 25 : 48;
    float pk0 = __int_as_float(__builtin_amdgcn_readlane(pbits, k0c));
    float pk1 = (kk2 < 24) ? __int_as_float(__builtin_amdgcn_readlane(pbits, k1c)) : 0.f;
    const int c0 = (k0c / 7) * 28 + (k0c % 7);
    const int c1 = (k1c / 7) * 28 + (k1c % 7);
    float pk = half ? pk1 : pk0;
    int nk = rowbase + (half ? c1 : c0);
    float term = pk * vb[(size_t)nk * 32];
    if (kk2 & 1) accB += term; else accA += term;
  }
  float acc = accA + accB;
  acc += __shfl_xor(acc, 32);
  if (l < 32)
    ob[(((size_t)b * 784 + m) * 6 + h) * 32 + l] = acc / sum;
}

extern "C" void kernel_launch(void* const* d_in, const int* in_sizes, int n_in,
                              void* d_out, int out_size, void* d_ws, size_t ws_size,
                              hipStream_t stream) {
  (void)in_sizes; (void)n_in; (void)out_size; (void)ws_size;
  const float* x        = (const float*)d_in[0];
  const float* convw    = (const float*)d_in[1];
  const float* qw       = (const float*)d_in[2];
  const float* kw       = (const float*)d_in[3];
  const float* vw       = (const float*)d_in[4];
  const float* ln_in_g  = (const float*)d_in[5];
  const float* ln_in_b  = (const float*)d_in[6];
  const float* ln_out_g = (const float*)d_in[7];
  const float* ln_out_b = (const float*)d_in[8];
  const float* ln_at_g  = (const float*)d_in[9];
  const float* ln_at_b  = (const float*)d_in[10];
  const float* ln_ml_g  = (const float*)d_in[11];
  const float* ln_ml_b  = (const float*)d_in[12];
  const float* gw1      = (const float*)d_in[13];
  const float* gb1      = (const float*)d_in[14];
  const float* gw2      = (const float*)d_in[15];
  const float* gb2      = (const float*)d_in[16];
  const float* tau      = (const float*)d_in[17];
  const float* rpb      = (const float*)d_in[18];
  const float* bln1g    = (const float*)d_in[19];
  const float* bln1b    = (const float*)d_in[20];
  const float* bln2g    = (const float*)d_in[21];
  const float* bln2b    = (const float*)d_in[22];
  const float* bqkvw    = (const float*)d_in[23];
  const float* bprojw   = (const float*)d_in[24];
  const float* bprojb   = (const float*)d_in[25];
  const float* bmw1     = (const float*)d_in[26];
  const float* bmb1     = (const float*)d_in[27];
  const float* bmw2     = (const float*)d_in[28];
  const float* bmb2     = (const float*)d_in[29];

  float* XOUT = (float*)d_out;  // residual stream lives in d_out (f32, 8*784*192)

  float* W = (float*)d_ws;
  size_t off = 0;
  float* Kb    = W + off; off += (size_t)25088 * 96;
  float* Vb    = W + off; off += (size_t)25088 * 192;
  float* Qb    = W + off; off += (size_t)6272 * 96;
  float* Mb    = W + off; off += (size_t)25088;
  float* Zb    = W + off; off += (size_t)25088;
  float* H1    = W + off; off += (size_t)6272 * 576;
  float* T2    = W + off; off += (size_t)6272 * 192;   // also CRAW
  float* CT    = W + off; off += (size_t)784 * 16;
  float* ST    = W + off; off += (size_t)784 * 16;
  float2* S96  = (float2*)(W + off); off += (size_t)25088 * 2;
  float2* S192 = (float2*)(W + off); off += (size_t)6272 * 2;
  short* WBH   = (short*)(W + off); off += (size_t)548352 + 16;  // hi arena
  short* WBL   = (short*)(W + off); off += (size_t)548352 + 16;  // lo arena
  const size_t O_c = 0, O_k = 165888, O_v = 175104, O_q = 193536,
               O_g1 = 211968, O_g2 = 285696, O_qkv = 359424, O_p = 580608,
               O_m1 = 654336, O_m2 = 875520;
  // aliases (group-phase buffers dead in block phase)
  float* CRAW = T2;
  float* Q3 = Kb;
  float* K3 = Kb + (size_t)1204224;
  float* V3 = Vb;
  float* OB = Vb + (size_t)1204224;

  k_castw<<<4284, 256, 0, stream>>>(convw, kw, vw, qw, gw1, gw2, bqkvw, bprojw,
                                    bmw1, bmw2, WBH, WBL);
  k_rope<<<49, 256, 0, stream>>>(CT, ST);

  // conv (implicit GEMM, K=864, tap-major weights) + LN (emits S192 for it=0 qproj)
  k_mgemm<0, 1, 0><<<dim3(196, 3), 128, 0, stream>>>(x, WBH + O_c, WBL + O_c, nullptr,
      CRAW, 6272, 192, 864, nullptr, nullptr, nullptr,
      nullptr, nullptr, nullptr, nullptr, nullptr);
  k_ln_epi<0><<<1568, 256, 0, stream>>>(CRAW, ln_out_g, ln_out_b, XOUT, S192, 6272);

  // k,v projections with fused LN via row stats
  k_lnstat<96><<<6272, 256, 0, stream>>>(x, S96, 25088);
  k_mgemm<0, 0, 1><<<dim3(784, 2), 128, 0, stream>>>(x, WBH + O_k, WBL + O_k, nullptr,
      Kb, 25088, 96, 96, S96, ln_in_g, ln_in_b,
      nullptr, nullptr, nullptr, nullptr, nullptr);
  k_mgemm<0, 0, 1><<<dim3(784, 3), 128, 0, stream>>>(x, WBH + O_v, WBL + O_v, nullptr,
      Vb, 25088, 192, 96, S96, ln_in_g, ln_in_b,
      nullptr, nullptr, nullptr, nullptr, nullptr);

  for (int it = 0; it < 3; ++it) {
    // S192 valid for current XOUT (from conv ln_epi or previous ln_epi<1>)
    k_mgemm<0, 0, 1><<<dim3(196, 2), 128, 0, stream>>>(XOUT, WBH + O_q, WBL + O_q, nullptr,
        Qb, 6272, 96, 192, S192, ln_out_g, ln_out_b,
        nullptr, nullptr, nullptr, nullptr, nullptr);
    k_pass1<<<6272, 256, 0, stream>>>(Kb, Qb, rpb, tau, Mb, Zb);
    k_pass2<<<6272, 256, 0, stream>>>(Kb, Qb, Vb, Mb, Zb, rpb, tau, ln_at_g, ln_at_b, XOUT);
    k_mgemm<1, 0, 0><<<dim3(196, 6), 128, 0, stream>>>(XOUT, WBH + O_g1, WBL + O_g1, gb1,
        H1, 6272, 384, 192, nullptr, nullptr, nullptr,
        nullptr, nullptr, nullptr, nullptr, nullptr);
    k_mgemm<0, 0, 0><<<dim3(196, 3), 128, 0, stream>>>(H1, WBH + O_g2, WBL + O_g2, gb2,
        T2, 6272, 192, 384, nullptr, nullptr, nullptr,
        nullptr, nullptr, nullptr, nullptr, nullptr);
    k_ln_epi<1><<<1568, 256, 0, stream>>>(T2, ln_ml_g, ln_ml_b, XOUT, S192, 6272);
  }

  for (int i = 0; i < 2; ++i) {
    if (i == 1) k_lnstat<192><<<1568, 256, 0, stream>>>(XOUT, S192, 6272);
    // qkv GEMM with fused LN prologue + rope+scatter epilogue (EPI=3)
    k_mgemm<3, 0, 1><<<dim3(196, 9), 128, 0, stream>>>(XOUT, WBH + O_qkv + (size_t)i * 110592,
        WBL + O_qkv + (size_t)i * 110592, nullptr,
        nullptr, 6272, 576, 192, S192, bln1g + (size_t)i * 192, bln1b + (size_t)i * 192,
        CT, ST, Q3, K3, V3);
    k_attn<<<9408, 256, 0, stream>>>(Q3, K3, V3, OB);
    k_mgemm<2, 0, 0><<<dim3(196, 3), 128, 0, stream>>>(OB, WBH + O_p + (size_t)i * 36864,
        WBL + O_p + (size_t)i * 36864, bprojb + (size_t)i * 192,
        XOUT, 6272, 192, 192, nullptr, nullptr, nullptr,
        nullptr, nullptr, nullptr, nullptr, nullptr);
    k_lnstat<192><<<1568, 256, 0, stream>>>(XOUT, S192, 6272);
    k_mgemm<1, 0, 1><<<dim3(196, 9), 128, 0, stream>>>(XOUT, WBH + O_m1 + (size_t)i * 110592,
        WBL + O_m1 + (size_t)i * 110592, bmb1 + (size_t)i * 576,
        H1, 6272, 576, 192, S192, bln2g + (size_t)i * 192, bln2b + (size_t)i * 192,
        nullptr, nullptr, nullptr, nullptr, nullptr);
    k_mgemm<2, 0, 0><<<dim3(196, 3), 128, 0, stream>>>(H1, WBH + O_m2 + (size_t)i * 110592,
        WBL + O_m2 + (size_t)i * 110592, bmb2 + (size_t)i * 192,
        XOUT, 6272, 192, 576, nullptr, nullptr, nullptr,
        nullptr, nullptr, nullptr, nullptr, nullptr);
  }
}

// Round 19
// 624.055 us; speedup vs baseline: 1.1910x; 1.1910x over previous
//
#include <hip/hip_runtime.h>
#include <hip/hip_bf16.h>

#define DEV __device__ __forceinline__

typedef __attribute__((ext_vector_type(8))) short short8;
typedef __attribute__((ext_vector_type(4))) float f32x4;

DEV unsigned short f2b(float f) {
  union { float f; unsigned u; } v; v.f = f;
  unsigned r = v.u + 0x7FFFu + ((v.u >> 16) & 1u);  // RNE
  return (unsigned short)(r >> 16);
}
DEV float b2f16(unsigned short b) {
  union { unsigned u; float f; } v; v.u = ((unsigned)b) << 16;
  return v.f;
}
// cheap truncation split: hi+lo carry ~16 mantissa bits (error ~2^-17 rel)
DEV void tsplit(float v, short& h, short& l) {
  union { float f; unsigned u; } c; c.f = v;
  unsigned short hu = (unsigned short)(c.u >> 16);
  union { unsigned u; float f; } hb; hb.u = (unsigned)hu << 16;
  union { float f; unsigned u; } c2; c2.f = v - hb.f;
  h = (short)hu; l = (short)(c2.u >> 16);
}

// ---------------- fused weight cast f32 -> bf16 hi/lo arenas (RNE, one-time) ----------------
// conv weights are stored TAP-MAJOR: dst[co*864 + k9*96 + ci] = src[co*864 + ci*9 + k9]
__global__ void k_castw(const float* __restrict__ s0, const float* __restrict__ s1,
    const float* __restrict__ s2, const float* __restrict__ s3,
    const float* __restrict__ s4, const float* __restrict__ s5,
    const float* __restrict__ s6, const float* __restrict__ s7,
    const float* __restrict__ s8, const float* __restrict__ s9,
    short* __restrict__ dh, short* __restrict__ dl) {
  int idx = blockIdx.x * 256 + threadIdx.x;
  if (idx >= 1096704) return;
  float v;
  if (idx < 165888) {
    int co = idx / 864, rem = idx % 864;
    int k9 = rem / 96, ci = rem % 96;
    v = s0[co * 864 + ci * 9 + k9];
  } else {
    const float* src; int base;
    if      (idx < 175104) { src = s1; base = 165888; }
    else if (idx < 193536) { src = s2; base = 175104; }
    else if (idx < 211968) { src = s3; base = 193536; }
    else if (idx < 285696) { src = s4; base = 211968; }
    else if (idx < 359424) { src = s5; base = 285696; }
    else if (idx < 580608) { src = s6; base = 359424; }
    else if (idx < 654336) { src = s7; base = 580608; }
    else if (idx < 875520) { src = s8; base = 654336; }
    else                   { src = s9; base = 875520; }
    v = src[idx - base];
  }
  unsigned short h = f2b(v);
  dh[idx] = (short)h;
  dl[idx] = (short)f2b(v - b2f16(h));
}

// ---------------- rope tables: ct/st [784][16] ----------------
__global__ void k_rope(float* ct, float* st) {
  int idx = blockIdx.x * 256 + threadIdx.x;
  if (idx >= 784 * 16) return;
  int n = idx >> 4, j = idx & 15;
  float inv = powf(10000.f, -(float)(2 * j) / 32.f);
  float ang = (float)n * inv;
  ct[idx] = cosf(ang);
  st[idx] = sinf(ang);
}

// ---------------- LN row stats: (mean, rstd) per row ----------------
template<int D>
__global__ __launch_bounds__(256) void k_lnstat(const float* __restrict__ in,
    float2* __restrict__ stats, int M) {
  int tok = blockIdx.x * 4 + (threadIdx.x >> 6);
  int l = threadIdx.x & 63;
  if (tok >= M) return;  // wave-uniform
  const float* row = in + (size_t)tok * D;
  constexpr int E = (D + 63) / 64;
  float s = 0.f, s2 = 0.f;
#pragma unroll
  for (int e = 0; e < E; ++e) {
    int i = e * 64 + l;
    float x = (i < D) ? row[i] : 0.f;
    s += x; s2 += x * x;
  }
  for (int off = 32; off; off >>= 1) { s += __shfl_xor(s, off); s2 += __shfl_xor(s2, off); }
  float mean = s / D, var = s2 / D - mean * mean;
  if (l == 0) stats[tok] = make_float2(mean, rsqrtf(var + 1e-5f));
}

// ---------------- LN epilogue over D=192: out = (write|add) LN(raw); emits row stats ----------------
template<int ADD>
__global__ __launch_bounds__(256) void k_ln_epi(const float* __restrict__ raw,
    const float* __restrict__ g, const float* __restrict__ b,
    float* __restrict__ out, float2* __restrict__ stats, int M) {
  int tok = blockIdx.x * 4 + (threadIdx.x >> 6);
  int l = threadIdx.x & 63;
  if (tok >= M) return;
  const float* row = raw + (size_t)tok * 192;
  float v[3];
  float s = 0.f, s2 = 0.f;
#pragma unroll
  for (int e = 0; e < 3; ++e) {
    float x = row[e * 64 + l];
    v[e] = x; s += x; s2 += x * x;
  }
  for (int off = 32; off; off >>= 1) { s += __shfl_xor(s, off); s2 += __shfl_xor(s2, off); }
  float mean = s / 192.f, var = s2 / 192.f - mean * mean;
  float rstd = rsqrtf(var + 1e-5f);
  float* orow = out + (size_t)tok * 192;
  float t = 0.f, t2 = 0.f;
#pragma unroll
  for (int e = 0; e < 3; ++e) {
    int i = e * 64 + l;
    float r = (v[e] - mean) * rstd * g[i] + b[i];
    float nv = ADD ? (orow[i] + r) : r;
    orow[i] = nv;
    t += nv; t2 += nv * nv;
  }
  for (int off = 32; off; off >>= 1) { t += __shfl_xor(t, off); t2 += __shfl_xor(t2, off); }
  float m2 = t / 192.f, v2 = t2 / 192.f - m2 * m2;
  if (l == 0) stats[tok] = make_float2(m2, rsqrtf(v2 + 1e-5f));
}

// ---------------- MFMA bf16x2 split GEMM: C = (LN?)(A) @ W^T ----------------
// tile 32(M) x 64(N), BK=32, 128 threads = 2 waves; wave w owns N-half (32 cols),
// 2x2 16x16 frags per wave. acc = ah*bh + ah*bl + al*bh.
// EPI: 0 store | 1 gelu+store | 2 add-into-C | 3 rope-scatter to o1/o2/o3 (qkv).
// CONV: im2col, weights TAP-MAJOR. LNS: apply LN to A rows using precomputed stats.
template<int EPI, int CONV, int LNS>
__global__ __launch_bounds__(128) void k_mgemm(
    const float* __restrict__ A, const short* __restrict__ WH,
    const short* __restrict__ WL, const float* __restrict__ bias,
    float* __restrict__ C, int M, int N, int K,
    const float2* __restrict__ lnstats, const float* __restrict__ lng,
    const float* __restrict__ lnb,
    const float* __restrict__ ct, const float* __restrict__ st,
    float* __restrict__ o1, float* __restrict__ o2, float* __restrict__ o3) {
  __shared__ short AsH[32][40], AsL[32][40];
  __shared__ short BsH[64][40], BsL[64][40];
  int t = threadIdx.x;
  int m0 = blockIdx.x * 32, n0 = blockIdx.y * 64;
  int sr = t >> 2, sq = (t & 3) * 8;       // A stage: row [0,32), k-offset (8/thread)
  int sr2 = t >> 1, sq2 = (t & 1) * 16;    // B stage: row [0,64), k-half (16/thread)
  int lane = t & 63, w = t >> 6;           // wave w in {0,1} -> N-half
  int fr = lane & 15, fq = lane >> 4;      // frag row, k-block
  float2 lst = make_float2(0.f, 1.f);
  if (LNS) lst = lnstats[m0 + sr];
  f32x4 acc[2][2];
#pragma unroll
  for (int i = 0; i < 2; ++i)
#pragma unroll
    for (int j = 0; j < 2; ++j) acc[i][j] = (f32x4){0.f, 0.f, 0.f, 0.f};

  for (int kt = 0; kt < K; kt += 32) {
    // ---- A tile: 32 rows x 32 k -> hi/lo bf16 (truncation split), 16B LDS writes ----
    short8 vh, vl;
    if (CONV) {
      int m = m0 + sr;
      int b = m / 784, rm = m % 784, ho = rm / 28, wo = rm % 28;
      int k = kt + sq;                      // octet never straddles a tap (96 % 8 == 0)
      int k9 = k / 96, ci0 = k % 96;
      int hi = 2 * ho - 1 + k9 / 3, wi = 2 * wo - 1 + k9 % 3;
      if (hi >= 0 && hi < 56 && wi >= 0 && wi < 56) {
        const float* src = &A[((size_t)b * 3136 + hi * 56 + wi) * 96 + ci0];
        float4 a0 = *(const float4*)src;
        float4 a1 = *(const float4*)(src + 4);
        float av[8] = {a0.x, a0.y, a0.z, a0.w, a1.x, a1.y, a1.z, a1.w};
#pragma unroll
        for (int j = 0; j < 8; ++j) { short h, l2; tsplit(av[j], h, l2); vh[j] = h; vl[j] = l2; }
      } else {
#pragma unroll
        for (int j = 0; j < 8; ++j) { vh[j] = 0; vl[j] = 0; }
      }
    } else {
      const float4 a0 = *(const float4*)&A[(size_t)(m0 + sr) * K + kt + sq];
      const float4 a1 = *(const float4*)&A[(size_t)(m0 + sr) * K + kt + sq + 4];
      float av[8] = {a0.x, a0.y, a0.z, a0.w, a1.x, a1.y, a1.z, a1.w};
#pragma unroll
      for (int j = 0; j < 8; ++j) {
        if (LNS) av[j] = (av[j] - lst.x) * lst.y * lng[kt + sq + j] + lnb[kt + sq + j];
        short h, l2; tsplit(av[j], h, l2); vh[j] = h; vl[j] = l2;
      }
    }
    *(short8*)&AsH[sr][sq] = vh;
    *(short8*)&AsL[sr][sq] = vl;
    // ---- B tile: row sr2, k-half sq2 (two short8 loads) ----
    {
      int n = n0 + sr2;
      if (n < N) {
        *(short8*)&BsH[sr2][sq2]     = *(const short8*)&WH[(size_t)n * K + kt + sq2];
        *(short8*)&BsH[sr2][sq2 + 8] = *(const short8*)&WH[(size_t)n * K + kt + sq2 + 8];
        *(short8*)&BsL[sr2][sq2]     = *(const short8*)&WL[(size_t)n * K + kt + sq2];
        *(short8*)&BsL[sr2][sq2 + 8] = *(const short8*)&WL[(size_t)n * K + kt + sq2 + 8];
      } else {
        short8 z = {0, 0, 0, 0, 0, 0, 0, 0};
        *(short8*)&BsH[sr2][sq2] = z; *(short8*)&BsH[sr2][sq2 + 8] = z;
        *(short8*)&BsL[sr2][sq2] = z; *(short8*)&BsL[sr2][sq2 + 8] = z;
      }
    }
    __syncthreads();
    short8 ah[2], al[2], bh[2], bl[2];
#pragma unroll
    for (int s = 0; s < 2; ++s) {
      ah[s] = *(const short8*)&AsH[s * 16 + fr][fq * 8];
      al[s] = *(const short8*)&AsL[s * 16 + fr][fq * 8];
      bh[s] = *(const short8*)&BsH[w * 32 + s * 16 + fr][fq * 8];
      bl[s] = *(const short8*)&BsL[w * 32 + s * 16 + fr][fq * 8];
    }
#pragma unroll
    for (int i = 0; i < 2; ++i)
#pragma unroll
      for (int j = 0; j < 2; ++j) {
        acc[i][j] = __builtin_amdgcn_mfma_f32_16x16x32_bf16(ah[i], bh[j], acc[i][j], 0, 0, 0);
        acc[i][j] = __builtin_amdgcn_mfma_f32_16x16x32_bf16(ah[i], bl[j], acc[i][j], 0, 0, 0);
        acc[i][j] = __builtin_amdgcn_mfma_f32_16x16x32_bf16(al[i], bh[j], acc[i][j], 0, 0, 0);
      }
    __syncthreads();
  }
  // epilogue: C/D layout col = lane&15, row = (lane>>4)*4 + r   [m89]
#pragma unroll
  for (int i = 0; i < 2; ++i) {
#pragma unroll
    for (int j = 0; j < 2; ++j) {
      int n = n0 + w * 32 + j * 16 + fr;
#pragma unroll
      for (int r = 0; r < 4; ++r) {
        int m = m0 + i * 16 + fq * 4 + r;
        float v = acc[i][j][r];
        float pa = 0.f;
        if (EPI == 3) pa = __shfl_xor(v, 1);  // rope partner (n^1 <-> lane^1); all lanes
        if (n >= N) continue;
        if (bias) v += bias[n];
        if (EPI == 1) v = 0.5f * v * (1.f + erff(v * 0.70710678118654752f));
        if (EPI == 3) {
          int sec = n / 192, d = n % 192, h = d / 32, dh = d % 32;
          int b = m / 784, mm = m % 784;
          float val;
          if (sec < 2) {
            int jj = dh >> 1;
            float cc = ct[mm * 16 + jj], ss = st[mm * 16 + jj];
            val = (dh & 1) ? (v * cc + pa * ss) : (v * cc - pa * ss);
          } else val = v;
          float* dst = (sec == 0) ? o1 : ((sec == 1) ? o2 : o3);
          dst[(((size_t)b * 6 + h) * 784 + mm) * 32 + dh] = val;
        } else if (EPI == 2) {
          C[(size_t)m * N + n] += v;
        } else {
          C[(size_t)m * N + n] = v;
        }
      }
    }
  }
}

// ---------------- pass1: wave-per-token softmax stats over deduped <=9 neighbors ----------------
__global__ __launch_bounds__(256) void k_pass1(const float* __restrict__ kk,
    const float* __restrict__ q, const float* __restrict__ rpb,
    const float* __restrict__ tau, float* __restrict__ M, float* __restrict__ Z) {
  int tok = blockIdx.x * 4 + (threadIdx.x >> 6);   // [0, 25088)
  int l = threadIdx.x & 63;
  int b = tok / 3136, n = tok % 3136;
  int r = n / 56, c = n % 56, r0 = r >> 1, c0 = c >> 1;
  int oi[9]; bool keep[9];
#pragma unroll
  for (int kki = 0; kki < 9; ++kki) {
    int dr = kki / 3 - 1, dc = kki % 3 - 1;
    int rr = min(max(r0 + dr, 0), 27), cc = min(max(c0 + dc, 0), 27);
    oi[kki] = rr * 28 + cc;
  }
#pragma unroll
  for (int kki = 0; kki < 9; ++kki) {
    bool kp = true;
#pragma unroll
    for (int k2 = kki + 1; k2 < 9; ++k2) if (oi[k2] == oi[kki]) kp = false;
    keep[kki] = kp;
  }
  float scale = expf(tau[0]);
  const float* kr = kk + (size_t)tok * 96;
  float k0 = kr[l];
  float k1 = (l < 32) ? kr[64 + l] : 0.f;
  float lg[9];
  float mx = -1e30f;
#pragma unroll
  for (int kki = 0; kki < 9; ++kki) {
    if (keep[kki]) {
      const float* qr = q + ((size_t)b * 784 + oi[kki]) * 96;
      float part = k0 * qr[l];
      if (l < 32) part += k1 * qr[64 + l];
      for (int off = 32; off; off >>= 1) part += __shfl_xor(part, off);
      lg[kki] = part * scale + rpb[kki];
      mx = fmaxf(mx, lg[kki]);
    } else lg[kki] = -1e30f;
  }
  float z = 0.f;
#pragma unroll
  for (int kki = 0; kki < 9; ++kki) if (keep[kki]) z += expf(lg[kki] - mx);
  if (l == 0) { M[tok] = mx; Z[tok] = z; }
}

// ---------------- pass2: gather contributors, upd, /denom, LN, residual (R17 form) ----------------
// XCD-chunked block swizzle: 6272 = 8*784 -> each XCD gets a contiguous m-range
// so adjacent outputs' shared gather rows hit the same private L2 (T1).
__global__ __launch_bounds__(192) void k_pass2(const float* __restrict__ kk,
    const float* __restrict__ q, const float* __restrict__ vv,
    const float* __restrict__ M, const float* __restrict__ Z,
    const float* __restrict__ rpb, const float* __restrict__ tau,
    const float* __restrict__ g, const float* __restrict__ bb, float* __restrict__ xout) {
  int bid = blockIdx.x;
  int blk = (bid & 7) * 784 + (bid >> 3);   // bijective on [0,6272)
  int b = blk / 784, m = blk % 784;
  int r2 = m / 28, c2 = m % 28;
  int r0lo = (r2 == 0) ? 0 : r2 - 1, r0hi = (r2 == 27) ? 27 : r2 + 1;
  int c0lo = (c2 == 0) ? 0 : c2 - 1, c0hi = (c2 == 27) ? 27 : c2 + 1;
  int nrow = 2 * (r0hi - r0lo + 1), ncol = 2 * (c0hi - c0lo + 1);
  int cnt = nrow * ncol;  // <= 36
  __shared__ float qm[96], p[36];
  __shared__ int nlist[36];
  __shared__ float2 red[192];
  int t = threadIdx.x;
  if (t < 96) qm[t] = q[(size_t)blk * 96 + t];
  __syncthreads();
  if (t < cnt) {
    int rr = 2 * r0lo + t / ncol, cc = 2 * c0lo + t % ncol;
    int n = rr * 56 + cc, rr0 = rr >> 1, cc0 = cc >> 1;
    int kkf = 0;
#pragma unroll
    for (int kki = 0; kki < 9; ++kki) {
      int dr = kki / 3 - 1, dc = kki % 3 - 1;
      int ra = min(max(rr0 + dr, 0), 27), ca = min(max(cc0 + dc, 0), 27);
      if (ra == r2 && ca == c2) kkf = kki;  // last-kk-wins (matches numpy overwrite)
    }
    const float* krow = kk + ((size_t)b * 3136 + n) * 96;
    float d = 0.f;
    for (int i = 0; i < 96; ++i) d += krow[i] * qm[i];
    float scale = expf(tau[0]);
    float lg = d * scale + rpb[kkf];
    size_t idn = (size_t)b * 3136 + n;
    p[t] = expf(lg - M[idn]) / Z[idn];
    nlist[t] = n;
  }
  __syncthreads();
  float denom = 0.f;
  for (int jn = 0; jn < cnt; ++jn) denom += p[jn];
  float acc = 0.f;
  for (int jn = 0; jn < cnt; ++jn)
    acc += p[jn] * vv[((size_t)b * 3136 + nlist[jn]) * 192 + t];
  float upd = acc / (denom + 1e-8f);
  red[t] = make_float2(upd, upd * upd);
  __syncthreads();
  for (int s = 128; s > 0; s >>= 1) {
    if (t < s && t + s < 192) { red[t].x += red[t + s].x; red[t].y += red[t + s].y; }
    __syncthreads();
  }
  float mean = red[0].x / 192.f, var = red[0].y / 192.f - mean * mean;
  float rstd = rsqrtf(var + 1e-5f);
  xout[(size_t)blk * 192 + t] += (upd - mean) * rstd * g[t] + bb[t];
}

// ---------------- neighborhood attention 7x7: literal-readlane pair-PV, dual acc ----------------
__global__ __launch_bounds__(256) void k_attn(const float* __restrict__ q3,
    const float* __restrict__ k3, const float* __restrict__ v3, float* __restrict__ ob) {
  int bid = blockIdx.x;
  int swz = (bid & 7) * 1176 + (bid >> 3);  // bijective on [0,9408)
  int unit = swz * 4 + (threadIdx.x >> 6);
  int l = threadIdx.x & 63;
  int b = unit / (6 * 784), rem = unit % (6 * 784), h = rem / 784, m = rem % 784;
  int i = m / 28, j = m % 28;
  int ib = min(max(i, 3), 24) - 3, jb = min(max(j, 3), 24) - 3;
  size_t base = (size_t)(b * 6 + h) * 784 * 32;
  const float4* q4 = (const float4*)(q3 + base + (size_t)m * 32);
  float4 qv[8];
#pragma unroll
  for (int e = 0; e < 8; ++e) qv[e] = q4[e];
  float logit = -1e30f;
  if (l < 49) {
    int nk = (ib + l / 7) * 28 + (jb + l % 7);
    const float4* k4 = (const float4*)(k3 + base + (size_t)nk * 32);
    float a = 0.f;
#pragma unroll
    for (int e = 0; e < 8; ++e) {
      float4 kv = k4[e];
      a += qv[e].x * kv.x + qv[e].y * kv.y + qv[e].z * kv.z + qv[e].w * kv.w;
    }
    logit = a * 0.17677669529663687f;  // 32^-0.5
  }
  float mx = logit;
  for (int off = 32; off; off >>= 1) mx = fmaxf(mx, __shfl_xor(mx, off));
  float p = (l < 49) ? expf(logit - mx) : 0.f;
  float sum = p;
  for (int off = 32; off; off >>= 1) sum += __shfl_xor(sum, off);
  int half = l >> 5, d = l & 31;
  const float* vb = v3 + base + d;
  int rowbase = ib * 28 + jb;
  float accA = 0.f, accB = 0.f;
  int pbits = __float_as_int(p);
#pragma unroll
  for (int kk2 = 0; kk2 < 25; ++kk2) {
    const int k0c = kk2;
    const int k1c = (kk2 + 25 <= 48) ? kk2 + 25 : 48;
    float pk0 = __int_as_float(__builtin_amdgcn_readlane(pbits, k0c));
    float pk1 = (kk2 < 24) ? __int_as_float(__builtin_amdgcn_readlane(pbits, k1c)) : 0.f;
    const int c0 = (k0c / 7) * 28 + (k0c % 7);
    const int c1 = (k1c / 7) * 28 + (k1c % 7);
    float pk = half ? pk1 : pk0;
    int nk = rowbase + (half ? c1 : c0);
    float term = pk * vb[(size_t)nk * 32];
    if (kk2 & 1) accB += term; else accA += term;
  }
  float acc = accA + accB;
  acc += __shfl_xor(acc, 32);
  if (l < 32)
    ob[(((size_t)b * 784 + m) * 6 + h) * 32 + l] = acc / sum;
}

extern "C" void kernel_launch(void* const* d_in, const int* in_sizes, int n_in,
                              void* d_out, int out_size, void* d_ws, size_t ws_size,
                              hipStream_t stream) {
  (void)in_sizes; (void)n_in; (void)out_size; (void)ws_size;
  const float* x        = (const float*)d_in[0];
  const float* convw    = (const float*)d_in[1];
  const float* qw       = (const float*)d_in[2];
  const float* kw       = (const float*)d_in[3];
  const float* vw       = (const float*)d_in[4];
  const float* ln_in_g  = (const float*)d_in[5];
  const float* ln_in_b  = (const float*)d_in[6];
  const float* ln_out_g = (const float*)d_in[7];
  const float* ln_out_b = (const float*)d_in[8];
  const float* ln_at_g  = (const float*)d_in[9];
  const float* ln_at_b  = (const float*)d_in[10];
  const float* ln_ml_g  = (const float*)d_in[11];
  const float* ln_ml_b  = (const float*)d_in[12];
  const float* gw1      = (const float*)d_in[13];
  const float* gb1      = (const float*)d_in[14];
  const float* gw2      = (const float*)d_in[15];
  const float* gb2      = (const float*)d_in[16];
  const float* tau      = (const float*)d_in[17];
  const float* rpb      = (const float*)d_in[18];
  const float* bln1g    = (const float*)d_in[19];
  const float* bln1b    = (const float*)d_in[20];
  const float* bln2g    = (const float*)d_in[21];
  const float* bln2b    = (const float*)d_in[22];
  const float* bqkvw    = (const float*)d_in[23];
  const float* bprojw   = (const float*)d_in[24];
  const float* bprojb   = (const float*)d_in[25];
  const float* bmw1     = (const float*)d_in[26];
  const float* bmb1     = (const float*)d_in[27];
  const float* bmw2     = (const float*)d_in[28];
  const float* bmb2     = (const float*)d_in[29];

  float* XOUT = (float*)d_out;  // residual stream lives in d_out (f32, 8*784*192)

  float* W = (float*)d_ws;
  size_t off = 0;
  float* Kb    = W + off; off += (size_t)25088 * 96;
  float* Vb    = W + off; off += (size_t)25088 * 192;
  float* Qb    = W + off; off += (size_t)6272 * 96;
  float* Mb    = W + off; off += (size_t)25088;
  float* Zb    = W + off; off += (size_t)25088;
  float* H1    = W + off; off += (size_t)6272 * 576;
  float* T2    = W + off; off += (size_t)6272 * 192;   // also CRAW
  float* CT    = W + off; off += (size_t)784 * 16;
  float* ST    = W + off; off += (size_t)784 * 16;
  float2* S96  = (float2*)(W + off); off += (size_t)25088 * 2;
  float2* S192 = (float2*)(W + off); off += (size_t)6272 * 2;
  short* WBH   = (short*)(W + off); off += (size_t)548352 + 16;  // hi arena
  short* WBL   = (short*)(W + off); off += (size_t)548352 + 16;  // lo arena
  const size_t O_c = 0, O_k = 165888, O_v = 175104, O_q = 193536,
               O_g1 = 211968, O_g2 = 285696, O_qkv = 359424, O_p = 580608,
               O_m1 = 654336, O_m2 = 875520;
  // aliases (group-phase buffers dead in block phase)
  float* CRAW = T2;
  float* Q3 = Kb;
  float* K3 = Kb + (size_t)1204224;
  float* V3 = Vb;
  float* OB = Vb + (size_t)1204224;

  k_castw<<<4284, 256, 0, stream>>>(convw, kw, vw, qw, gw1, gw2, bqkvw, bprojw,
                                    bmw1, bmw2, WBH, WBL);
  k_rope<<<49, 256, 0, stream>>>(CT, ST);

  // conv (implicit GEMM, K=864, tap-major weights) + LN (emits S192 for it=0 qproj)
  k_mgemm<0, 1, 0><<<dim3(196, 3), 128, 0, stream>>>(x, WBH + O_c, WBL + O_c, nullptr,
      CRAW, 6272, 192, 864, nullptr, nullptr, nullptr,
      nullptr, nullptr, nullptr, nullptr, nullptr);
  k_ln_epi<0><<<1568, 256, 0, stream>>>(CRAW, ln_out_g, ln_out_b, XOUT, S192, 6272);

  // k,v projections with fused LN via row stats
  k_lnstat<96><<<6272, 256, 0, stream>>>(x, S96, 25088);
  k_mgemm<0, 0, 1><<<dim3(784, 2), 128, 0, stream>>>(x, WBH + O_k, WBL + O_k, nullptr,
      Kb, 25088, 96, 96, S96, ln_in_g, ln_in_b,
      nullptr, nullptr, nullptr, nullptr, nullptr);
  k_mgemm<0, 0, 1><<<dim3(784, 3), 128, 0, stream>>>(x, WBH + O_v, WBL + O_v, nullptr,
      Vb, 25088, 192, 96, S96, ln_in_g, ln_in_b,
      nullptr, nullptr, nullptr, nullptr, nullptr);

  for (int it = 0; it < 3; ++it) {
    // S192 valid for current XOUT (from conv ln_epi or previous ln_epi<1>)
    k_mgemm<0, 0, 1><<<dim3(196, 2), 128, 0, stream>>>(XOUT, WBH + O_q, WBL + O_q, nullptr,
        Qb, 6272, 96, 192, S192, ln_out_g, ln_out_b,
        nullptr, nullptr, nullptr, nullptr, nullptr);
    k_pass1<<<6272, 256, 0, stream>>>(Kb, Qb, rpb, tau, Mb, Zb);
    k_pass2<<<6272, 192, 0, stream>>>(Kb, Qb, Vb, Mb, Zb, rpb, tau, ln_at_g, ln_at_b, XOUT);
    k_mgemm<1, 0, 0><<<dim3(196, 6), 128, 0, stream>>>(XOUT, WBH + O_g1, WBL + O_g1, gb1,
        H1, 6272, 384, 192, nullptr, nullptr, nullptr,
        nullptr, nullptr, nullptr, nullptr, nullptr);
    k_mgemm<0, 0, 0><<<dim3(196, 3), 128, 0, stream>>>(H1, WBH + O_g2, WBL + O_g2, gb2,
        T2, 6272, 192, 384, nullptr, nullptr, nullptr,
        nullptr, nullptr, nullptr, nullptr, nullptr);
    k_ln_epi<1><<<1568, 256, 0, stream>>>(T2, ln_ml_g, ln_ml_b, XOUT, S192, 6272);
  }

  for (int i = 0; i < 2; ++i) {
    if (i == 1) k_lnstat<192><<<1568, 256, 0, stream>>>(XOUT, S192, 6272);
    // qkv GEMM with fused LN prologue + rope+scatter epilogue (EPI=3)
    k_mgemm<3, 0, 1><<<dim3(196, 9), 128, 0, stream>>>(XOUT, WBH + O_qkv + (size_t)i * 110592,
        WBL + O_qkv + (size_t)i * 110592, nullptr,
        nullptr, 6272, 576, 192, S192, bln1g + (size_t)i * 192, bln1b + (size_t)i * 192,
        CT, ST, Q3, K3, V3);
    k_attn<<<9408, 256, 0, stream>>>(Q3, K3, V3, OB);
    k_mgemm<2, 0, 0><<<dim3(196, 3), 128, 0, stream>>>(OB, WBH + O_p + (size_t)i * 36864,
        WBL + O_p + (size_t)i * 36864, bprojb + (size_t)i * 192,
        XOUT, 6272, 192, 192, nullptr, nullptr, nullptr,
        nullptr, nullptr, nullptr, nullptr, nullptr);
    k_lnstat<192><<<1568, 256, 0, stream>>>(XOUT, S192, 6272);
    k_mgemm<1, 0, 1><<<dim3(196, 9), 128, 0, stream>>>(XOUT, WBH + O_m1 + (size_t)i * 110592,
        WBL + O_m1 + (size_t)i * 110592, bmb1 + (size_t)i * 576,
        H1, 6272, 576, 192, S192, bln2g + (size_t)i * 192, bln2b + (size_t)i * 192,
        nullptr, nullptr, nullptr, nullptr, nullptr);
    k_mgemm<2, 0, 0><<<dim3(196, 3), 128, 0, stream>>>(H1, WBH + O_m2 + (size_t)i * 110592,
        WBL + O_m2 + (size_t)i * 110592, bmb2 + (size_t)i * 192,
        XOUT, 6272, 192, 576, nullptr, nullptr, nullptr,
        nullptr, nullptr, nullptr, nullptr, nullptr);
  }
}

// Round 20
// 619.868 us; speedup vs baseline: 1.1990x; 1.0068x over previous
//
#include <hip/hip_runtime.h>
#include <hip/hip_bf16.h>

#define DEV __device__ __forceinline__

typedef __attribute__((ext_vector_type(8))) short short8;
typedef __attribute__((ext_vector_type(4))) float f32x4;

DEV unsigned short f2b(float f) {
  union { float f; unsigned u; } v; v.f = f;
  unsigned r = v.u + 0x7FFFu + ((v.u >> 16) & 1u);  // RNE
  return (unsigned short)(r >> 16);
}
DEV float b2f16(unsigned short b) {
  union { unsigned u; float f; } v; v.u = ((unsigned)b) << 16;
  return v.f;
}
// cheap truncation split: hi+lo carry ~16 mantissa bits (error ~2^-17 rel)
DEV void tsplit(float v, short& h, short& l) {
  union { float f; unsigned u; } c; c.f = v;
  unsigned short hu = (unsigned short)(c.u >> 16);
  union { unsigned u; float f; } hb; hb.u = (unsigned)hu << 16;
  union { float f; unsigned u; } c2; c2.f = v - hb.f;
  h = (short)hu; l = (short)(c2.u >> 16);
}

// ---------------- fused weight cast f32 -> bf16 hi/lo arenas (RNE, one-time) ----------------
// conv weights are stored TAP-MAJOR: dst[co*864 + k9*96 + ci] = src[co*864 + ci*9 + k9]
__global__ void k_castw(const float* __restrict__ s0, const float* __restrict__ s1,
    const float* __restrict__ s2, const float* __restrict__ s3,
    const float* __restrict__ s4, const float* __restrict__ s5,
    const float* __restrict__ s6, const float* __restrict__ s7,
    const float* __restrict__ s8, const float* __restrict__ s9,
    short* __restrict__ dh, short* __restrict__ dl) {
  int idx = blockIdx.x * 256 + threadIdx.x;
  if (idx >= 1096704) return;
  float v;
  if (idx < 165888) {
    int co = idx / 864, rem = idx % 864;
    int k9 = rem / 96, ci = rem % 96;
    v = s0[co * 864 + ci * 9 + k9];
  } else {
    const float* src; int base;
    if      (idx < 175104) { src = s1; base = 165888; }
    else if (idx < 193536) { src = s2; base = 175104; }
    else if (idx < 211968) { src = s3; base = 193536; }
    else if (idx < 285696) { src = s4; base = 211968; }
    else if (idx < 359424) { src = s5; base = 285696; }
    else if (idx < 580608) { src = s6; base = 359424; }
    else if (idx < 654336) { src = s7; base = 580608; }
    else if (idx < 875520) { src = s8; base = 654336; }
    else                   { src = s9; base = 875520; }
    v = src[idx - base];
  }
  unsigned short h = f2b(v);
  dh[idx] = (short)h;
  dl[idx] = (short)f2b(v - b2f16(h));
}

// ---------------- rope tables: ct/st [784][16] ----------------
__global__ void k_rope(float* ct, float* st) {
  int idx = blockIdx.x * 256 + threadIdx.x;
  if (idx >= 784 * 16) return;
  int n = idx >> 4, j = idx & 15;
  float inv = powf(10000.f, -(float)(2 * j) / 32.f);
  float ang = (float)n * inv;
  ct[idx] = cosf(ang);
  st[idx] = sinf(ang);
}

// ---------------- LN row stats: (mean, rstd) per row ----------------
template<int D>
__global__ __launch_bounds__(256) void k_lnstat(const float* __restrict__ in,
    float2* __restrict__ stats, int M) {
  int tok = blockIdx.x * 4 + (threadIdx.x >> 6);
  int l = threadIdx.x & 63;
  if (tok >= M) return;  // wave-uniform
  const float* row = in + (size_t)tok * D;
  constexpr int E = (D + 63) / 64;
  float s = 0.f, s2 = 0.f;
#pragma unroll
  for (int e = 0; e < E; ++e) {
    int i = e * 64 + l;
    float x = (i < D) ? row[i] : 0.f;
    s += x; s2 += x * x;
  }
  for (int off = 32; off; off >>= 1) { s += __shfl_xor(s, off); s2 += __shfl_xor(s2, off); }
  float mean = s / D, var = s2 / D - mean * mean;
  if (l == 0) stats[tok] = make_float2(mean, rsqrtf(var + 1e-5f));
}

// ---------------- LN epilogue over D=192: out = (write|add) LN(raw); emits row stats ----------------
template<int ADD>
__global__ __launch_bounds__(256) void k_ln_epi(const float* __restrict__ raw,
    const float* __restrict__ g, const float* __restrict__ b,
    float* __restrict__ out, float2* __restrict__ stats, int M) {
  int tok = blockIdx.x * 4 + (threadIdx.x >> 6);
  int l = threadIdx.x & 63;
  if (tok >= M) return;
  const float* row = raw + (size_t)tok * 192;
  float v[3];
  float s = 0.f, s2 = 0.f;
#pragma unroll
  for (int e = 0; e < 3; ++e) {
    float x = row[e * 64 + l];
    v[e] = x; s += x; s2 += x * x;
  }
  for (int off = 32; off; off >>= 1) { s += __shfl_xor(s, off); s2 += __shfl_xor(s2, off); }
  float mean = s / 192.f, var = s2 / 192.f - mean * mean;
  float rstd = rsqrtf(var + 1e-5f);
  float* orow = out + (size_t)tok * 192;
  float t = 0.f, t2 = 0.f;
#pragma unroll
  for (int e = 0; e < 3; ++e) {
    int i = e * 64 + l;
    float r = (v[e] - mean) * rstd * g[i] + b[i];
    float nv = ADD ? (orow[i] + r) : r;
    orow[i] = nv;
    t += nv; t2 += nv * nv;
  }
  for (int off = 32; off; off >>= 1) { t += __shfl_xor(t, off); t2 += __shfl_xor(t2, off); }
  float m2 = t / 192.f, v2 = t2 / 192.f - m2 * m2;
  if (l == 0) stats[tok] = make_float2(m2, rsqrtf(v2 + 1e-5f));
}

// ---------------- MFMA bf16x2 split GEMM: C = (LN?)(A) @ W^T ----------------
// tile 32(M) x 64(N), BK=32, 128 threads = 2 waves; wave w owns N-half (32 cols),
// 2x2 16x16 frags per wave. acc = ah*bh + ah*bl + al*bh.
// EPI: 0 store | 1 gelu+store | 2 add-into-C | 3 rope-scatter to o1/o2/o3 (qkv)
//      | 5 split store: n<96 -> o1[m][96], else o2[m][192] (fused K/V projection).
// CONV: im2col, weights TAP-MAJOR. LNS: apply LN to A rows using precomputed stats.
template<int EPI, int CONV, int LNS>
__global__ __launch_bounds__(128) void k_mgemm(
    const float* __restrict__ A, const short* __restrict__ WH,
    const short* __restrict__ WL, const float* __restrict__ bias,
    float* __restrict__ C, int M, int N, int K,
    const float2* __restrict__ lnstats, const float* __restrict__ lng,
    const float* __restrict__ lnb,
    const float* __restrict__ ct, const float* __restrict__ st,
    float* __restrict__ o1, float* __restrict__ o2, float* __restrict__ o3) {
  __shared__ short AsH[32][40], AsL[32][40];
  __shared__ short BsH[64][40], BsL[64][40];
  int t = threadIdx.x;
  int m0 = blockIdx.x * 32, n0 = blockIdx.y * 64;
  int sr = t >> 2, sq = (t & 3) * 8;       // A stage: row [0,32), k-offset (8/thread)
  int sr2 = t >> 1, sq2 = (t & 1) * 16;    // B stage: row [0,64), k-half (16/thread)
  int lane = t & 63, w = t >> 6;           // wave w in {0,1} -> N-half
  int fr = lane & 15, fq = lane >> 4;      // frag row, k-block
  float2 lst = make_float2(0.f, 1.f);
  if (LNS) lst = lnstats[m0 + sr];
  f32x4 acc[2][2];
#pragma unroll
  for (int i = 0; i < 2; ++i)
#pragma unroll
    for (int j = 0; j < 2; ++j) acc[i][j] = (f32x4){0.f, 0.f, 0.f, 0.f};

  for (int kt = 0; kt < K; kt += 32) {
    // ---- A tile: 32 rows x 32 k -> hi/lo bf16 (truncation split), 16B LDS writes ----
    short8 vh, vl;
    if (CONV) {
      int m = m0 + sr;
      int b = m / 784, rm = m % 784, ho = rm / 28, wo = rm % 28;
      int k = kt + sq;                      // octet never straddles a tap (96 % 8 == 0)
      int k9 = k / 96, ci0 = k % 96;
      int hi = 2 * ho - 1 + k9 / 3, wi = 2 * wo - 1 + k9 % 3;
      if (hi >= 0 && hi < 56 && wi >= 0 && wi < 56) {
        const float* src = &A[((size_t)b * 3136 + hi * 56 + wi) * 96 + ci0];
        float4 a0 = *(const float4*)src;
        float4 a1 = *(const float4*)(src + 4);
        float av[8] = {a0.x, a0.y, a0.z, a0.w, a1.x, a1.y, a1.z, a1.w};
#pragma unroll
        for (int j = 0; j < 8; ++j) { short h, l2; tsplit(av[j], h, l2); vh[j] = h; vl[j] = l2; }
      } else {
#pragma unroll
        for (int j = 0; j < 8; ++j) { vh[j] = 0; vl[j] = 0; }
      }
    } else {
      const float4 a0 = *(const float4*)&A[(size_t)(m0 + sr) * K + kt + sq];
      const float4 a1 = *(const float4*)&A[(size_t)(m0 + sr) * K + kt + sq + 4];
      float av[8] = {a0.x, a0.y, a0.z, a0.w, a1.x, a1.y, a1.z, a1.w};
#pragma unroll
      for (int j = 0; j < 8; ++j) {
        if (LNS) av[j] = (av[j] - lst.x) * lst.y * lng[kt + sq + j] + lnb[kt + sq + j];
        short h, l2; tsplit(av[j], h, l2); vh[j] = h; vl[j] = l2;
      }
    }
    *(short8*)&AsH[sr][sq] = vh;
    *(short8*)&AsL[sr][sq] = vl;
    // ---- B tile: row sr2, k-half sq2 (two short8 loads) ----
    {
      int n = n0 + sr2;
      if (n < N) {
        *(short8*)&BsH[sr2][sq2]     = *(const short8*)&WH[(size_t)n * K + kt + sq2];
        *(short8*)&BsH[sr2][sq2 + 8] = *(const short8*)&WH[(size_t)n * K + kt + sq2 + 8];
        *(short8*)&BsL[sr2][sq2]     = *(const short8*)&WL[(size_t)n * K + kt + sq2];
        *(short8*)&BsL[sr2][sq2 + 8] = *(const short8*)&WL[(size_t)n * K + kt + sq2 + 8];
      } else {
        short8 z = {0, 0, 0, 0, 0, 0, 0, 0};
        *(short8*)&BsH[sr2][sq2] = z; *(short8*)&BsH[sr2][sq2 + 8] = z;
        *(short8*)&BsL[sr2][sq2] = z; *(short8*)&BsL[sr2][sq2 + 8] = z;
      }
    }
    __syncthreads();
    short8 ah[2], al[2], bh[2], bl[2];
#pragma unroll
    for (int s = 0; s < 2; ++s) {
      ah[s] = *(const short8*)&AsH[s * 16 + fr][fq * 8];
      al[s] = *(const short8*)&AsL[s * 16 + fr][fq * 8];
      bh[s] = *(const short8*)&BsH[w * 32 + s * 16 + fr][fq * 8];
      bl[s] = *(const short8*)&BsL[w * 32 + s * 16 + fr][fq * 8];
    }
#pragma unroll
    for (int i = 0; i < 2; ++i)
#pragma unroll
      for (int j = 0; j < 2; ++j) {
        acc[i][j] = __builtin_amdgcn_mfma_f32_16x16x32_bf16(ah[i], bh[j], acc[i][j], 0, 0, 0);
        acc[i][j] = __builtin_amdgcn_mfma_f32_16x16x32_bf16(ah[i], bl[j], acc[i][j], 0, 0, 0);
        acc[i][j] = __builtin_amdgcn_mfma_f32_16x16x32_bf16(al[i], bh[j], acc[i][j], 0, 0, 0);
      }
    __syncthreads();
  }
  // epilogue: C/D layout col = lane&15, row = (lane>>4)*4 + r   [m89]
#pragma unroll
  for (int i = 0; i < 2; ++i) {
#pragma unroll
    for (int j = 0; j < 2; ++j) {
      int n = n0 + w * 32 + j * 16 + fr;
#pragma unroll
      for (int r = 0; r < 4; ++r) {
        int m = m0 + i * 16 + fq * 4 + r;
        float v = acc[i][j][r];
        float pa = 0.f;
        if (EPI == 3) pa = __shfl_xor(v, 1);  // rope partner (n^1 <-> lane^1); all lanes
        if (n >= N) continue;
        if (bias) v += bias[n];
        if (EPI == 1) v = 0.5f * v * (1.f + erff(v * 0.70710678118654752f));
        if (EPI == 3) {
          int sec = n / 192, d = n % 192, h = d / 32, dh = d % 32;
          int b = m / 784, mm = m % 784;
          float val;
          if (sec < 2) {
            int jj = dh >> 1;
            float cc = ct[mm * 16 + jj], ss = st[mm * 16 + jj];
            val = (dh & 1) ? (v * cc + pa * ss) : (v * cc - pa * ss);
          } else val = v;
          float* dst = (sec == 0) ? o1 : ((sec == 1) ? o2 : o3);
          dst[(((size_t)b * 6 + h) * 784 + mm) * 32 + dh] = val;
        } else if (EPI == 5) {
          if (n < 96) o1[(size_t)m * 96 + n] = v;
          else        o2[(size_t)m * 192 + (n - 96)] = v;
        } else if (EPI == 2) {
          C[(size_t)m * N + n] += v;
        } else {
          C[(size_t)m * N + n] = v;
        }
      }
    }
  }
}

// ---------------- pass1: wave-per-token softmax stats over deduped <=9 neighbors ----------------
__global__ __launch_bounds__(256) void k_pass1(const float* __restrict__ kk,
    const float* __restrict__ q, const float* __restrict__ rpb,
    const float* __restrict__ tau, float* __restrict__ M, float* __restrict__ Z) {
  int tok = blockIdx.x * 4 + (threadIdx.x >> 6);   // [0, 25088)
  int l = threadIdx.x & 63;
  int b = tok / 3136, n = tok % 3136;
  int r = n / 56, c = n % 56, r0 = r >> 1, c0 = c >> 1;
  int oi[9]; bool keep[9];
#pragma unroll
  for (int kki = 0; kki < 9; ++kki) {
    int dr = kki / 3 - 1, dc = kki % 3 - 1;
    int rr = min(max(r0 + dr, 0), 27), cc = min(max(c0 + dc, 0), 27);
    oi[kki] = rr * 28 + cc;
  }
#pragma unroll
  for (int kki = 0; kki < 9; ++kki) {
    bool kp = true;
#pragma unroll
    for (int k2 = kki + 1; k2 < 9; ++k2) if (oi[k2] == oi[kki]) kp = false;
    keep[kki] = kp;
  }
  float scale = expf(tau[0]);
  const float* kr = kk + (size_t)tok * 96;
  float k0 = kr[l];
  float k1 = (l < 32) ? kr[64 + l] : 0.f;
  float lg[9];
  float mx = -1e30f;
#pragma unroll
  for (int kki = 0; kki < 9; ++kki) {
    if (keep[kki]) {
      const float* qr = q + ((size_t)b * 784 + oi[kki]) * 96;
      float part = k0 * qr[l];
      if (l < 32) part += k1 * qr[64 + l];
      for (int off = 32; off; off >>= 1) part += __shfl_xor(part, off);
      lg[kki] = part * scale + rpb[kki];
      mx = fmaxf(mx, lg[kki]);
    } else lg[kki] = -1e30f;
  }
  float z = 0.f;
#pragma unroll
  for (int kki = 0; kki < 9; ++kki) if (keep[kki]) z += expf(lg[kki] - mx);
  if (l == 0) { M[tok] = mx; Z[tok] = z; }
}

// ---------------- pass2: gather contributors, upd, /denom, LN, residual ----------------
// XCD-chunked block swizzle: 6272 = 8*784 (T1 locality).
__global__ __launch_bounds__(192) void k_pass2(const float* __restrict__ kk,
    const float* __restrict__ q, const float* __restrict__ vv,
    const float* __restrict__ M, const float* __restrict__ Z,
    const float* __restrict__ rpb, const float* __restrict__ tau,
    const float* __restrict__ g, const float* __restrict__ bb, float* __restrict__ xout) {
  int bid = blockIdx.x;
  int blk = (bid & 7) * 784 + (bid >> 3);   // bijective on [0,6272)
  int b = blk / 784, m = blk % 784;
  int r2 = m / 28, c2 = m % 28;
  int r0lo = (r2 == 0) ? 0 : r2 - 1, r0hi = (r2 == 27) ? 27 : r2 + 1;
  int c0lo = (c2 == 0) ? 0 : c2 - 1, c0hi = (c2 == 27) ? 27 : c2 + 1;
  int nrow = 2 * (r0hi - r0lo + 1), ncol = 2 * (c0hi - c0lo + 1);
  int cnt = nrow * ncol;  // <= 36
  __shared__ float qm[96], p[36];
  __shared__ int nlist[36];
  __shared__ float2 red[192];
  int t = threadIdx.x;
  if (t < 96) qm[t] = q[(size_t)blk * 96 + t];
  __syncthreads();
  if (t < cnt) {
    int rr = 2 * r0lo + t / ncol, cc = 2 * c0lo + t % ncol;
    int n = rr * 56 + cc, rr0 = rr >> 1, cc0 = cc >> 1;
    int kkf = 0;
#pragma unroll
    for (int kki = 0; kki < 9; ++kki) {
      int dr = kki / 3 - 1, dc = kki % 3 - 1;
      int ra = min(max(rr0 + dr, 0), 27), ca = min(max(cc0 + dc, 0), 27);
      if (ra == r2 && ca == c2) kkf = kki;  // last-kk-wins (matches numpy overwrite)
    }
    const float* krow = kk + ((size_t)b * 3136 + n) * 96;
    float d = 0.f;
    for (int i = 0; i < 96; ++i) d += krow[i] * qm[i];
    float scale = expf(tau[0]);
    float lg = d * scale + rpb[kkf];
    size_t idn = (size_t)b * 3136 + n;
    p[t] = expf(lg - M[idn]) / Z[idn];
    nlist[t] = n;
  }
  __syncthreads();
  float denom = 0.f;
  for (int jn = 0; jn < cnt; ++jn) denom += p[jn];
  float acc = 0.f;
  for (int jn = 0; jn < cnt; ++jn)
    acc += p[jn] * vv[((size_t)b * 3136 + nlist[jn]) * 192 + t];
  float upd = acc / (denom + 1e-8f);
  red[t] = make_float2(upd, upd * upd);
  __syncthreads();
  for (int s = 128; s > 0; s >>= 1) {
    if (t < s && t + s < 192) { red[t].x += red[t + s].x; red[t].y += red[t + s].y; }
    __syncthreads();
  }
  float mean = red[0].x / 192.f, var = red[0].y / 192.f - mean * mean;
  float rstd = rsqrtf(var + 1e-5f);
  xout[(size_t)blk * 192 + t] += (upd - mean) * rstd * g[t] + bb[t];
}

// ---------------- neighborhood attention 7x7: readlane pair-PV, fused sum ----------------
__global__ __launch_bounds__(256) void k_attn(const float* __restrict__ q3,
    const float* __restrict__ k3, const float* __restrict__ v3, float* __restrict__ ob) {
  int bid = blockIdx.x;
  int swz = (bid & 7) * 1176 + (bid >> 3);  // bijective on [0,9408)
  int unit = swz * 4 + (threadIdx.x >> 6);
  int l = threadIdx.x & 63;
  int b = unit / (6 * 784), rem = unit % (6 * 784), h = rem / 784, m = rem % 784;
  int i = m / 28, j = m % 28;
  int ib = min(max(i, 3), 24) - 3, jb = min(max(j, 3), 24) - 3;
  size_t base = (size_t)(b * 6 + h) * 784 * 32;
  const float4* q4 = (const float4*)(q3 + base + (size_t)m * 32);
  float4 qv[8];
#pragma unroll
  for (int e = 0; e < 8; ++e) qv[e] = q4[e];
  float logit = -1e30f;
  if (l < 49) {
    int nk = (ib + l / 7) * 28 + (jb + l % 7);
    const float4* k4 = (const float4*)(k3 + base + (size_t)nk * 32);
    float a = 0.f;
#pragma unroll
    for (int e = 0; e < 8; ++e) {
      float4 kv = k4[e];
      a += qv[e].x * kv.x + qv[e].y * kv.y + qv[e].z * kv.z + qv[e].w * kv.w;
    }
    logit = a * 0.17677669529663687f;  // 32^-0.5
  }
  float mx = logit;
  for (int off = 32; off; off >>= 1) mx = fmaxf(mx, __shfl_xor(mx, off));
  float p = (l < 49) ? expf(logit - mx) : 0.f;
  // sum folded into PV loop (halves sum disjoint neighbor sets; combined with acc)
  int half = l >> 5, d = l & 31;
  const float* vb = v3 + base + d;
  int rowbase = ib * 28 + jb;
  float accA = 0.f, accB = 0.f, psum = 0.f;
  int pbits = __float_as_int(p);
#pragma unroll
  for (int kk2 = 0; kk2 < 25; ++kk2) {
    const int k0c = kk2;
    const int k1c = (kk2 + 25 <= 48) ? kk2 + 25 : 48;
    float pk0 = __int_as_float(__builtin_amdgcn_readlane(pbits, k0c));
    float pk1 = (kk2 < 24) ? __int_as_float(__builtin_amdgcn_readlane(pbits, k1c)) : 0.f;
    const int c0 = (k0c / 7) * 28 + (k0c % 7);
    const int c1 = (k1c / 7) * 28 + (k1c % 7);
    float pk = half ? pk1 : pk0;
    int nk = rowbase + (half ? c1 : c0);
    psum += pk;
    float term = pk * vb[(size_t)nk * 32];
    if (kk2 & 1) accB += term; else accA += term;
  }
  float acc = accA + accB;
  acc += __shfl_xor(acc, 32);
  psum += __shfl_xor(psum, 32);
  if (l < 32)
    ob[(((size_t)b * 784 + m) * 6 + h) * 32 + l] = acc / psum;
}

extern "C" void kernel_launch(void* const* d_in, const int* in_sizes, int n_in,
                              void* d_out, int out_size, void* d_ws, size_t ws_size,
                              hipStream_t stream) {
  (void)in_sizes; (void)n_in; (void)out_size; (void)ws_size;
  const float* x        = (const float*)d_in[0];
  const float* convw    = (const float*)d_in[1];
  const float* qw       = (const float*)d_in[2];
  const float* kw       = (const float*)d_in[3];
  const float* vw       = (const float*)d_in[4];
  const float* ln_in_g  = (const float*)d_in[5];
  const float* ln_in_b  = (const float*)d_in[6];
  const float* ln_out_g = (const float*)d_in[7];
  const float* ln_out_b = (const float*)d_in[8];
  const float* ln_at_g  = (const float*)d_in[9];
  const float* ln_at_b  = (const float*)d_in[10];
  const float* ln_ml_g  = (const float*)d_in[11];
  const float* ln_ml_b  = (const float*)d_in[12];
  const float* gw1      = (const float*)d_in[13];
  const float* gb1      = (const float*)d_in[14];
  const float* gw2      = (const float*)d_in[15];
  const float* gb2      = (const float*)d_in[16];
  const float* tau      = (const float*)d_in[17];
  const float* rpb      = (const float*)d_in[18];
  const float* bln1g    = (const float*)d_in[19];
  const float* bln1b    = (const float*)d_in[20];
  const float* bln2g    = (const float*)d_in[21];
  const float* bln2b    = (const float*)d_in[22];
  const float* bqkvw    = (const float*)d_in[23];
  const float* bprojw   = (const float*)d_in[24];
  const float* bprojb   = (const float*)d_in[25];
  const float* bmw1     = (const float*)d_in[26];
  const float* bmb1     = (const float*)d_in[27];
  const float* bmw2     = (const float*)d_in[28];
  const float* bmb2     = (const float*)d_in[29];

  float* XOUT = (float*)d_out;  // residual stream lives in d_out (f32, 8*784*192)

  float* W = (float*)d_ws;
  size_t off = 0;
  float* Kb    = W + off; off += (size_t)25088 * 96;
  float* Vb    = W + off; off += (size_t)25088 * 192;
  float* Qb    = W + off; off += (size_t)6272 * 96;
  float* Mb    = W + off; off += (size_t)25088;
  float* Zb    = W + off; off += (size_t)25088;
  float* H1    = W + off; off += (size_t)6272 * 576;
  float* T2    = W + off; off += (size_t)6272 * 192;   // also CRAW
  float* CT    = W + off; off += (size_t)784 * 16;
  float* ST    = W + off; off += (size_t)784 * 16;
  float2* S96  = (float2*)(W + off); off += (size_t)25088 * 2;
  float2* S192 = (float2*)(W + off); off += (size_t)6272 * 2;
  short* WBH   = (short*)(W + off); off += (size_t)548352 + 16;  // hi arena
  short* WBL   = (short*)(W + off); off += (size_t)548352 + 16;  // lo arena
  const size_t O_c = 0, O_k = 165888, O_v = 175104, O_q = 193536,
               O_g1 = 211968, O_g2 = 285696, O_qkv = 359424, O_p = 580608,
               O_m1 = 654336, O_m2 = 875520;
  (void)O_v;  // kw/vw are adjacent: WBH+O_k is a [288][96] matrix (96 K-rows + 192 V-rows)
  // aliases (group-phase buffers dead in block phase)
  float* CRAW = T2;
  float* Q3 = Kb;
  float* K3 = Kb + (size_t)1204224;
  float* V3 = Vb;
  float* OB = Vb + (size_t)1204224;

  k_castw<<<4284, 256, 0, stream>>>(convw, kw, vw, qw, gw1, gw2, bqkvw, bprojw,
                                    bmw1, bmw2, WBH, WBL);
  k_rope<<<49, 256, 0, stream>>>(CT, ST);

  // conv (implicit GEMM, K=864, tap-major weights) + LN (emits S192 for it=0 qproj)
  k_mgemm<0, 1, 0><<<dim3(196, 3), 128, 0, stream>>>(x, WBH + O_c, WBL + O_c, nullptr,
      CRAW, 6272, 192, 864, nullptr, nullptr, nullptr,
      nullptr, nullptr, nullptr, nullptr, nullptr);
  k_ln_epi<0><<<1568, 256, 0, stream>>>(CRAW, ln_out_g, ln_out_b, XOUT, S192, 6272);

  // fused K+V projection: one GEMM over the adjacent [288][96] weight block,
  // split-store epilogue (EPI=5) -> Kb / Vb; reads LN(x) once.
  k_lnstat<96><<<6272, 256, 0, stream>>>(x, S96, 25088);
  k_mgemm<5, 0, 1><<<dim3(784, 5), 128, 0, stream>>>(x, WBH + O_k, WBL + O_k, nullptr,
      nullptr, 25088, 288, 96, S96, ln_in_g, ln_in_b,
      nullptr, nullptr, Kb, Vb, nullptr);

  for (int it = 0; it < 3; ++it) {
    // S192 valid for current XOUT (from conv ln_epi or previous ln_epi<1>)
    k_mgemm<0, 0, 1><<<dim3(196, 2), 128, 0, stream>>>(XOUT, WBH + O_q, WBL + O_q, nullptr,
        Qb, 6272, 96, 192, S192, ln_out_g, ln_out_b,
        nullptr, nullptr, nullptr, nullptr, nullptr);
    k_pass1<<<6272, 256, 0, stream>>>(Kb, Qb, rpb, tau, Mb, Zb);
    k_pass2<<<6272, 192, 0, stream>>>(Kb, Qb, Vb, Mb, Zb, rpb, tau, ln_at_g, ln_at_b, XOUT);
    k_mgemm<1, 0, 0><<<dim3(196, 6), 128, 0, stream>>>(XOUT, WBH + O_g1, WBL + O_g1, gb1,
        H1, 6272, 384, 192, nullptr, nullptr, nullptr,
        nullptr, nullptr, nullptr, nullptr, nullptr);
    k_mgemm<0, 0, 0><<<dim3(196, 3), 128, 0, stream>>>(H1, WBH + O_g2, WBL + O_g2, gb2,
        T2, 6272, 192, 384, nullptr, nullptr, nullptr,
        nullptr, nullptr, nullptr, nullptr, nullptr);
    k_ln_epi<1><<<1568, 256, 0, stream>>>(T2, ln_ml_g, ln_ml_b, XOUT, S192, 6272);
  }

  for (int i = 0; i < 2; ++i) {
    if (i == 1) k_lnstat<192><<<1568, 256, 0, stream>>>(XOUT, S192, 6272);
    // qkv GEMM with fused LN prologue + rope+scatter epilogue (EPI=3)
    k_mgemm<3, 0, 1><<<dim3(196, 9), 128, 0, stream>>>(XOUT, WBH + O_qkv + (size_t)i * 110592,
        WBL + O_qkv + (size_t)i * 110592, nullptr,
        nullptr, 6272, 576, 192, S192, bln1g + (size_t)i * 192, bln1b + (size_t)i * 192,
        CT, ST, Q3, K3, V3);
    k_attn<<<9408, 256, 0, stream>>>(Q3, K3, V3, OB);
    k_mgemm<2, 0, 0><<<dim3(196, 3), 128, 0, stream>>>(OB, WBH + O_p + (size_t)i * 36864,
        WBL + O_p + (size_t)i * 36864, bprojb + (size_t)i * 192,
        XOUT, 6272, 192, 192, nullptr, nullptr, nullptr,
        nullptr, nullptr, nullptr, nullptr, nullptr);
    k_lnstat<192><<<1568, 256, 0, stream>>>(XOUT, S192, 6272);
    k_mgemm<1, 0, 1><<<dim3(196, 9), 128, 0, stream>>>(XOUT, WBH + O_m1 + (size_t)i * 110592,
        WBL + O_m1 + (size_t)i * 110592, bmb1 + (size_t)i * 576,
        H1, 6272, 576, 192, S192, bln2g + (size_t)i * 192, bln2b + (size_t)i * 192,
        nullptr, nullptr, nullptr, nullptr, nullptr);
    k_mgemm<2, 0, 0><<<dim3(196, 3), 128, 0, stream>>>(H1, WBH + O_m2 + (size_t)i * 110592,
        WBL + O_m2 + (size_t)i * 110592, bmb2 + (size_t)i * 192,
        XOUT, 6272, 192, 576, nullptr, nullptr, nullptr,
        nullptr, nullptr, nullptr, nullptr, nullptr);
  }
}

// Round 21
// 615.109 us; speedup vs baseline: 1.2083x; 1.0077x over previous
//
#include <hip/hip_runtime.h>
#include <hip/hip_bf16.h>

#define DEV __device__ __forceinline__

typedef __attribute__((ext_vector_type(8))) short short8;
typedef __attribute__((ext_vector_type(4))) float f32x4;

DEV unsigned short f2b(float f) {
  union { float f; unsigned u; } v; v.f = f;
  unsigned r = v.u + 0x7FFFu + ((v.u >> 16) & 1u);  // RNE
  return (unsigned short)(r >> 16);
}
DEV float b2f16(unsigned short b) {
  union { unsigned u; float f; } v; v.u = ((unsigned)b) << 16;
  return v.f;
}
// cheap truncation split: hi+lo carry ~16 mantissa bits (error ~2^-17 rel)
DEV void tsplit(float v, short& h, short& l) {
  union { float f; unsigned u; } c; c.f = v;
  unsigned short hu = (unsigned short)(c.u >> 16);
  union { unsigned u; float f; } hb; hb.u = (unsigned)hu << 16;
  union { float f; unsigned u; } c2; c2.f = v - hb.f;
  h = (short)hu; l = (short)(c2.u >> 16);
}

// ---------------- fused weight cast f32 -> bf16 hi/lo arenas (RNE, one-time) ----------------
// conv weights are stored TAP-MAJOR: dst[co*864 + k9*96 + ci] = src[co*864 + ci*9 + k9]
__global__ void k_castw(const float* __restrict__ s0, const float* __restrict__ s1,
    const float* __restrict__ s2, const float* __restrict__ s3,
    const float* __restrict__ s4, const float* __restrict__ s5,
    const float* __restrict__ s6, const float* __restrict__ s7,
    const float* __restrict__ s8, const float* __restrict__ s9,
    short* __restrict__ dh, short* __restrict__ dl) {
  int idx = blockIdx.x * 256 + threadIdx.x;
  if (idx >= 1096704) return;
  float v;
  if (idx < 165888) {
    int co = idx / 864, rem = idx % 864;
    int k9 = rem / 96, ci = rem % 96;
    v = s0[co * 864 + ci * 9 + k9];
  } else {
    const float* src; int base;
    if      (idx < 175104) { src = s1; base = 165888; }
    else if (idx < 193536) { src = s2; base = 175104; }
    else if (idx < 211968) { src = s3; base = 193536; }
    else if (idx < 285696) { src = s4; base = 211968; }
    else if (idx < 359424) { src = s5; base = 285696; }
    else if (idx < 580608) { src = s6; base = 359424; }
    else if (idx < 654336) { src = s7; base = 580608; }
    else if (idx < 875520) { src = s8; base = 654336; }
    else                   { src = s9; base = 875520; }
    v = src[idx - base];
  }
  unsigned short h = f2b(v);
  dh[idx] = (short)h;
  dl[idx] = (short)f2b(v - b2f16(h));
}

// ---------------- rope tables: ct/st [784][16] ----------------
__global__ void k_rope(float* ct, float* st) {
  int idx = blockIdx.x * 256 + threadIdx.x;
  if (idx >= 784 * 16) return;
  int n = idx >> 4, j = idx & 15;
  float inv = powf(10000.f, -(float)(2 * j) / 32.f);
  float ang = (float)n * inv;
  ct[idx] = cosf(ang);
  st[idx] = sinf(ang);
}

// ---------------- LN + split: xh/xl = split(LN(in; g,b)) ----------------
template<int D>
__global__ __launch_bounds__(256) void k_lnsplit(const float* __restrict__ in,
    const float* __restrict__ g, const float* __restrict__ b,
    short* __restrict__ xh, short* __restrict__ xl, int M) {
  int tok = blockIdx.x * 4 + (threadIdx.x >> 6);
  int l = threadIdx.x & 63;
  if (tok >= M) return;  // wave-uniform
  const float* row = in + (size_t)tok * D;
  constexpr int E = (D + 63) / 64;
  float v[E];
  float s = 0.f, s2 = 0.f;
#pragma unroll
  for (int e = 0; e < E; ++e) {
    int i = e * 64 + l;
    float x = (i < D) ? row[i] : 0.f;
    v[e] = x; s += x; s2 += x * x;
  }
  for (int off = 32; off; off >>= 1) { s += __shfl_xor(s, off); s2 += __shfl_xor(s2, off); }
  float mean = s / D, var = s2 / D - mean * mean;
  float rstd = rsqrtf(var + 1e-5f);
#pragma unroll
  for (int e = 0; e < E; ++e) {
    int i = e * 64 + l;
    if (i < D) {
      float r = (v[e] - mean) * rstd * g[i] + b[i];
      short h2, l2; tsplit(r, h2, l2);
      xh[(size_t)tok * D + i] = h2;
      xl[(size_t)tok * D + i] = l2;
    }
  }
}

// ---------------- LN epilogue D=192: out = (write|add) LN(raw; g,b);
// also emits split(LN(out; eg,eb)) for the next GEMM consumer ----------------
template<int ADD>
__global__ __launch_bounds__(256) void k_ln_epi(const float* __restrict__ raw,
    const float* __restrict__ g, const float* __restrict__ b,
    const float* __restrict__ eg, const float* __restrict__ eb,
    float* __restrict__ out, short* __restrict__ xh, short* __restrict__ xl, int M) {
  int tok = blockIdx.x * 4 + (threadIdx.x >> 6);
  int l = threadIdx.x & 63;
  if (tok >= M) return;
  const float* row = raw + (size_t)tok * 192;
  float v[3];
  float s = 0.f, s2 = 0.f;
#pragma unroll
  for (int e = 0; e < 3; ++e) {
    float x = row[e * 64 + l];
    v[e] = x; s += x; s2 += x * x;
  }
  for (int off = 32; off; off >>= 1) { s += __shfl_xor(s, off); s2 += __shfl_xor(s2, off); }
  float mean = s / 192.f, var = s2 / 192.f - mean * mean;
  float rstd = rsqrtf(var + 1e-5f);
  float* orow = out + (size_t)tok * 192;
  float nv[3];
  float t = 0.f, t2 = 0.f;
#pragma unroll
  for (int e = 0; e < 3; ++e) {
    int i = e * 64 + l;
    float r = (v[e] - mean) * rstd * g[i] + b[i];
    float x = ADD ? (orow[i] + r) : r;
    orow[i] = x;
    nv[e] = x;
    t += x; t2 += x * x;
  }
  for (int off = 32; off; off >>= 1) { t += __shfl_xor(t, off); t2 += __shfl_xor(t2, off); }
  float m2 = t / 192.f, v2 = t2 / 192.f - m2 * m2;
  float rstd2 = rsqrtf(v2 + 1e-5f);
#pragma unroll
  for (int e = 0; e < 3; ++e) {
    int i = e * 64 + l;
    float r = (nv[e] - m2) * rstd2 * eg[i] + eb[i];
    short h2, l2; tsplit(r, h2, l2);
    xh[(size_t)tok * 192 + i] = h2;
    xl[(size_t)tok * 192 + i] = l2;
  }
}

// ---------------- MFMA bf16x2 split GEMM: C = A @ W^T ----------------
// tile 32(M) x 64(N), BK=32, 128 threads = 2 waves; wave w owns N-half.
// acc = ah*bh + ah*bl + al*bh.
// SRC: 0 = conv f32 im2col (tap-major weights), 1 = pre-split bf16 A (AH/AL).
// EPI: 0 store f32 | 1 gelu -> split store to oh/ol | 2 add-into-C
//      | 3 rope-scatter to o1/o2/o3 (qkv) | 5 split K/V store (n<96 -> o1, else o2).
template<int EPI, int SRC>
__global__ __launch_bounds__(128) void k_mgemm(
    const float* __restrict__ Aconv, const short* __restrict__ AH,
    const short* __restrict__ AL, const short* __restrict__ WH,
    const short* __restrict__ WL, const float* __restrict__ bias,
    float* __restrict__ C, int M, int N, int K,
    const float* __restrict__ ct, const float* __restrict__ st,
    float* __restrict__ o1, float* __restrict__ o2, float* __restrict__ o3,
    short* __restrict__ oh, short* __restrict__ ol) {
  __shared__ short AsH[32][40], AsL[32][40];
  __shared__ short BsH[64][40], BsL[64][40];
  int t = threadIdx.x;
  int m0 = blockIdx.x * 32, n0 = blockIdx.y * 64;
  int sr = t >> 2, sq = (t & 3) * 8;       // A stage: row [0,32), k-offset (8/thread)
  int sr2 = t >> 1, sq2 = (t & 1) * 16;    // B stage: row [0,64), k-half (16/thread)
  int lane = t & 63, w = t >> 6;           // wave w in {0,1} -> N-half
  int fr = lane & 15, fq = lane >> 4;      // frag row, k-block
  f32x4 acc[2][2];
#pragma unroll
  for (int i = 0; i < 2; ++i)
#pragma unroll
    for (int j = 0; j < 2; ++j) acc[i][j] = (f32x4){0.f, 0.f, 0.f, 0.f};

  for (int kt = 0; kt < K; kt += 32) {
    // ---- A tile ----
    if (SRC == 1) {
      *(short8*)&AsH[sr][sq] = *(const short8*)&AH[(size_t)(m0 + sr) * K + kt + sq];
      *(short8*)&AsL[sr][sq] = *(const short8*)&AL[(size_t)(m0 + sr) * K + kt + sq];
    } else {
      short8 vh, vl;
      int m = m0 + sr;
      int b = m / 784, rm = m % 784, ho = rm / 28, wo = rm % 28;
      int k = kt + sq;                      // octet never straddles a tap (96 % 8 == 0)
      int k9 = k / 96, ci0 = k % 96;
      int hi = 2 * ho - 1 + k9 / 3, wi = 2 * wo - 1 + k9 % 3;
      if (hi >= 0 && hi < 56 && wi >= 0 && wi < 56) {
        const float* src = &Aconv[((size_t)b * 3136 + hi * 56 + wi) * 96 + ci0];
        float4 a0 = *(const float4*)src;
        float4 a1 = *(const float4*)(src + 4);
        float av[8] = {a0.x, a0.y, a0.z, a0.w, a1.x, a1.y, a1.z, a1.w};
#pragma unroll
        for (int j = 0; j < 8; ++j) { short h, l2; tsplit(av[j], h, l2); vh[j] = h; vl[j] = l2; }
      } else {
#pragma unroll
        for (int j = 0; j < 8; ++j) { vh[j] = 0; vl[j] = 0; }
      }
      *(short8*)&AsH[sr][sq] = vh;
      *(short8*)&AsL[sr][sq] = vl;
    }
    // ---- B tile: row sr2, k-half sq2 ----
    {
      int n = n0 + sr2;
      if (n < N) {
        *(short8*)&BsH[sr2][sq2]     = *(const short8*)&WH[(size_t)n * K + kt + sq2];
        *(short8*)&BsH[sr2][sq2 + 8] = *(const short8*)&WH[(size_t)n * K + kt + sq2 + 8];
        *(short8*)&BsL[sr2][sq2]     = *(const short8*)&WL[(size_t)n * K + kt + sq2];
        *(short8*)&BsL[sr2][sq2 + 8] = *(const short8*)&WL[(size_t)n * K + kt + sq2 + 8];
      } else {
        short8 z = {0, 0, 0, 0, 0, 0, 0, 0};
        *(short8*)&BsH[sr2][sq2] = z; *(short8*)&BsH[sr2][sq2 + 8] = z;
        *(short8*)&BsL[sr2][sq2] = z; *(short8*)&BsL[sr2][sq2 + 8] = z;
      }
    }
    __syncthreads();
    short8 ah[2], al[2], bh[2], bl[2];
#pragma unroll
    for (int s = 0; s < 2; ++s) {
      ah[s] = *(const short8*)&AsH[s * 16 + fr][fq * 8];
      al[s] = *(const short8*)&AsL[s * 16 + fr][fq * 8];
      bh[s] = *(const short8*)&BsH[w * 32 + s * 16 + fr][fq * 8];
      bl[s] = *(const short8*)&BsL[w * 32 + s * 16 + fr][fq * 8];
    }
#pragma unroll
    for (int i = 0; i < 2; ++i)
#pragma unroll
      for (int j = 0; j < 2; ++j) {
        acc[i][j] = __builtin_amdgcn_mfma_f32_16x16x32_bf16(ah[i], bh[j], acc[i][j], 0, 0, 0);
        acc[i][j] = __builtin_amdgcn_mfma_f32_16x16x32_bf16(ah[i], bl[j], acc[i][j], 0, 0, 0);
        acc[i][j] = __builtin_amdgcn_mfma_f32_16x16x32_bf16(al[i], bh[j], acc[i][j], 0, 0, 0);
      }
    __syncthreads();
  }
  // epilogue: C/D layout col = lane&15, row = (lane>>4)*4 + r   [m89]
#pragma unroll
  for (int i = 0; i < 2; ++i) {
#pragma unroll
    for (int j = 0; j < 2; ++j) {
      int n = n0 + w * 32 + j * 16 + fr;
#pragma unroll
      for (int r = 0; r < 4; ++r) {
        int m = m0 + i * 16 + fq * 4 + r;
        float v = acc[i][j][r];
        float pa = 0.f;
        if (EPI == 3) pa = __shfl_xor(v, 1);  // rope partner (n^1 <-> lane^1); all lanes
        if (n >= N) continue;
        if (bias) v += bias[n];
        if (EPI == 1) {
          v = 0.5f * v * (1.f + erff(v * 0.70710678118654752f));
          short h2, l2; tsplit(v, h2, l2);
          oh[(size_t)m * N + n] = h2;
          ol[(size_t)m * N + n] = l2;
        } else if (EPI == 3) {
          int sec = n / 192, d = n % 192, h = d / 32, dh = d % 32;
          int b = m / 784, mm = m % 784;
          float val;
          if (sec < 2) {
            int jj = dh >> 1;
            float cc = ct[mm * 16 + jj], ss = st[mm * 16 + jj];
            val = (dh & 1) ? (v * cc + pa * ss) : (v * cc - pa * ss);
          } else val = v;
          float* dst = (sec == 0) ? o1 : ((sec == 1) ? o2 : o3);
          dst[(((size_t)b * 6 + h) * 784 + mm) * 32 + dh] = val;
        } else if (EPI == 5) {
          if (n < 96) o1[(size_t)m * 96 + n] = v;
          else        o2[(size_t)m * 192 + (n - 96)] = v;
        } else if (EPI == 2) {
          C[(size_t)m * N + n] += v;
        } else {
          C[(size_t)m * N + n] = v;
        }
      }
    }
  }
}

// ---------------- pass1: wave-per-token softmax stats over deduped <=9 neighbors ----------------
__global__ __launch_bounds__(256) void k_pass1(const float* __restrict__ kk,
    const float* __restrict__ q, const float* __restrict__ rpb,
    const float* __restrict__ tau, float* __restrict__ M, float* __restrict__ Z) {
  int tok = blockIdx.x * 4 + (threadIdx.x >> 6);   // [0, 25088)
  int l = threadIdx.x & 63;
  int b = tok / 3136, n = tok % 3136;
  int r = n / 56, c = n % 56, r0 = r >> 1, c0 = c >> 1;
  int oi[9]; bool keep[9];
#pragma unroll
  for (int kki = 0; kki < 9; ++kki) {
    int dr = kki / 3 - 1, dc = kki % 3 - 1;
    int rr = min(max(r0 + dr, 0), 27), cc = min(max(c0 + dc, 0), 27);
    oi[kki] = rr * 28 + cc;
  }
#pragma unroll
  for (int kki = 0; kki < 9; ++kki) {
    bool kp = true;
#pragma unroll
    for (int k2 = kki + 1; k2 < 9; ++k2) if (oi[k2] == oi[kki]) kp = false;
    keep[kki] = kp;
  }
  float scale = expf(tau[0]);
  const float* kr = kk + (size_t)tok * 96;
  float k0 = kr[l];
  float k1 = (l < 32) ? kr[64 + l] : 0.f;
  float lg[9];
  float mx = -1e30f;
#pragma unroll
  for (int kki = 0; kki < 9; ++kki) {
    if (keep[kki]) {
      const float* qr = q + ((size_t)b * 784 + oi[kki]) * 96;
      float part = k0 * qr[l];
      if (l < 32) part += k1 * qr[64 + l];
      for (int off = 32; off; off >>= 1) part += __shfl_xor(part, off);
      lg[kki] = part * scale + rpb[kki];
      mx = fmaxf(mx, lg[kki]);
    } else lg[kki] = -1e30f;
  }
  float z = 0.f;
#pragma unroll
  for (int kki = 0; kki < 9; ++kki) if (keep[kki]) z += expf(lg[kki] - mx);
  if (l == 0) { M[tok] = mx; Z[tok] = z; }
}

// ---------------- pass2: gather, upd, /denom, LN, residual; emits raw-XOUT split ----------------
// XCD-chunked block swizzle: 6272 = 8*784 (T1 locality).
__global__ __launch_bounds__(192) void k_pass2(const float* __restrict__ kk,
    const float* __restrict__ q, const float* __restrict__ vv,
    const float* __restrict__ M, const float* __restrict__ Z,
    const float* __restrict__ rpb, const float* __restrict__ tau,
    const float* __restrict__ g, const float* __restrict__ bb,
    float* __restrict__ xout, short* __restrict__ xh, short* __restrict__ xl) {
  int bid = blockIdx.x;
  int blk = (bid & 7) * 784 + (bid >> 3);   // bijective on [0,6272)
  int b = blk / 784, m = blk % 784;
  int r2 = m / 28, c2 = m % 28;
  int r0lo = (r2 == 0) ? 0 : r2 - 1, r0hi = (r2 == 27) ? 27 : r2 + 1;
  int c0lo = (c2 == 0) ? 0 : c2 - 1, c0hi = (c2 == 27) ? 27 : c2 + 1;
  int nrow = 2 * (r0hi - r0lo + 1), ncol = 2 * (c0hi - c0lo + 1);
  int cnt = nrow * ncol;  // <= 36
  __shared__ float qm[96], p[36];
  __shared__ int nlist[36];
  __shared__ float2 red[192];
  int t = threadIdx.x;
  if (t < 96) qm[t] = q[(size_t)blk * 96 + t];
  __syncthreads();
  if (t < cnt) {
    int rr = 2 * r0lo + t / ncol, cc = 2 * c0lo + t % ncol;
    int n = rr * 56 + cc, rr0 = rr >> 1, cc0 = cc >> 1;
    int kkf = 0;
#pragma unroll
    for (int kki = 0; kki < 9; ++kki) {
      int dr = kki / 3 - 1, dc = kki % 3 - 1;
      int ra = min(max(rr0 + dr, 0), 27), ca = min(max(cc0 + dc, 0), 27);
      if (ra == r2 && ca == c2) kkf = kki;  // last-kk-wins (matches numpy overwrite)
    }
    const float* krow = kk + ((size_t)b * 3136 + n) * 96;
    float d = 0.f;
    for (int i = 0; i < 96; ++i) d += krow[i] * qm[i];
    float scale = expf(tau[0]);
    float lg = d * scale + rpb[kkf];
    size_t idn = (size_t)b * 3136 + n;
    p[t] = expf(lg - M[idn]) / Z[idn];
    nlist[t] = n;
  }
  __syncthreads();
  float denom = 0.f;
  for (int jn = 0; jn < cnt; ++jn) denom += p[jn];
  float acc = 0.f;
  for (int jn = 0; jn < cnt; ++jn)
    acc += p[jn] * vv[((size_t)b * 3136 + nlist[jn]) * 192 + t];
  float upd = acc / (denom + 1e-8f);
  red[t] = make_float2(upd, upd * upd);
  __syncthreads();
  for (int s = 128; s > 0; s >>= 1) {
    if (t < s && t + s < 192) { red[t].x += red[t + s].x; red[t].y += red[t + s].y; }
    __syncthreads();
  }
  float mean = red[0].x / 192.f, var = red[0].y / 192.f - mean * mean;
  float rstd = rsqrtf(var + 1e-5f);
  float nv = xout[(size_t)blk * 192 + t] + (upd - mean) * rstd * g[t] + bb[t];
  xout[(size_t)blk * 192 + t] = nv;
  short h2, l2; tsplit(nv, h2, l2);
  xh[(size_t)blk * 192 + t] = h2;
  xl[(size_t)blk * 192 + t] = l2;
}

// ---------------- neighborhood attention 7x7: readlane pair-PV, fused sum, split out ----------------
__global__ __launch_bounds__(256) void k_attn(const float* __restrict__ q3,
    const float* __restrict__ k3, const float* __restrict__ v3,
    short* __restrict__ obh, short* __restrict__ obl) {
  int bid = blockIdx.x;
  int swz = (bid & 7) * 1176 + (bid >> 3);  // bijective on [0,9408)
  int unit = swz * 4 + (threadIdx.x >> 6);
  int l = threadIdx.x & 63;
  int b = unit / (6 * 784), rem = unit % (6 * 784), h = rem / 784, m = rem % 784;
  int i = m / 28, j = m % 28;
  int ib = min(max(i, 3), 24) - 3, jb = min(max(j, 3), 24) - 3;
  size_t base = (size_t)(b * 6 + h) * 784 * 32;
  const float4* q4 = (const float4*)(q3 + base + (size_t)m * 32);
  float4 qv[8];
#pragma unroll
  for (int e = 0; e < 8; ++e) qv[e] = q4[e];
  float logit = -1e30f;
  if (l < 49) {
    int nk = (ib + l / 7) * 28 + (jb + l % 7);
    const float4* k4 = (const float4*)(k3 + base + (size_t)nk * 32);
    float a = 0.f;
#pragma unroll
    for (int e = 0; e < 8; ++e) {
      float4 kv = k4[e];
      a += qv[e].x * kv.x + qv[e].y * kv.y + qv[e].z * kv.z + qv[e].w * kv.w;
    }
    logit = a * 0.17677669529663687f;  // 32^-0.5
  }
  float mx = logit;
  for (int off = 32; off; off >>= 1) mx = fmaxf(mx, __shfl_xor(mx, off));
  float p = (l < 49) ? expf(logit - mx) : 0.f;
  int half = l >> 5, d = l & 31;
  const float* vb = v3 + base + d;
  int rowbase = ib * 28 + jb;
  float accA = 0.f, accB = 0.f, psum = 0.f;
  int pbits = __float_as_int(p);
#pragma unroll
  for (int kk2 = 0; kk2 < 25; ++kk2) {
    const int k0c = kk2;
    const int k1c = (kk2 + 25 <= 48) ? kk2 + 25 : 48;
    float pk0 = __int_as_float(__builtin_amdgcn_readlane(pbits, k0c));
    float pk1 = (kk2 < 24) ? __int_as_float(__builtin_amdgcn_readlane(pbits, k1c)) : 0.f;
    const int c0 = (k0c / 7) * 28 + (k0c % 7);
    const int c1 = (k1c / 7) * 28 + (k1c % 7);
    float pk = half ? pk1 : pk0;
    int nk = rowbase + (half ? c1 : c0);
    psum += pk;
    float term = pk * vb[(size_t)nk * 32];
    if (kk2 & 1) accB += term; else accA += term;
  }
  float acc = accA + accB;
  acc += __shfl_xor(acc, 32);
  psum += __shfl_xor(psum, 32);
  if (l < 32) {
    float o = acc / psum;
    short h2, l2; tsplit(o, h2, l2);
    size_t idx = (((size_t)b * 784 + m) * 6 + h) * 32 + l;
    obh[idx] = h2;
    obl[idx] = l2;
  }
}

extern "C" void kernel_launch(void* const* d_in, const int* in_sizes, int n_in,
                              void* d_out, int out_size, void* d_ws, size_t ws_size,
                              hipStream_t stream) {
  (void)in_sizes; (void)n_in; (void)out_size; (void)ws_size;
  const float* x        = (const float*)d_in[0];
  const float* convw    = (const float*)d_in[1];
  const float* qw       = (const float*)d_in[2];
  const float* kw       = (const float*)d_in[3];
  const float* vw       = (const float*)d_in[4];
  const float* ln_in_g  = (const float*)d_in[5];
  const float* ln_in_b  = (const float*)d_in[6];
  const float* ln_out_g = (const float*)d_in[7];
  const float* ln_out_b = (const float*)d_in[8];
  const float* ln_at_g  = (const float*)d_in[9];
  const float* ln_at_b  = (const float*)d_in[10];
  const float* ln_ml_g  = (const float*)d_in[11];
  const float* ln_ml_b  = (const float*)d_in[12];
  const float* gw1      = (const float*)d_in[13];
  const float* gb1      = (const float*)d_in[14];
  const float* gw2      = (const float*)d_in[15];
  const float* gb2      = (const float*)d_in[16];
  const float* tau      = (const float*)d_in[17];
  const float* rpb      = (const float*)d_in[18];
  const float* bln1g    = (const float*)d_in[19];
  const float* bln1b    = (const float*)d_in[20];
  const float* bln2g    = (const float*)d_in[21];
  const float* bln2b    = (const float*)d_in[22];
  const float* bqkvw    = (const float*)d_in[23];
  const float* bprojw   = (const float*)d_in[24];
  const float* bprojb   = (const float*)d_in[25];
  const float* bmw1     = (const float*)d_in[26];
  const float* bmb1     = (const float*)d_in[27];
  const float* bmw2     = (const float*)d_in[28];
  const float* bmb2     = (const float*)d_in[29];

  float* XOUT = (float*)d_out;  // residual stream lives in d_out (f32, 8*784*192)

  float* W = (float*)d_ws;
  size_t off = 0;
  float* Kb    = W + off; off += (size_t)25088 * 96;
  float* Vb    = W + off; off += (size_t)25088 * 192;
  float* Qb    = W + off; off += (size_t)6272 * 96;
  float* Mb    = W + off; off += (size_t)25088;
  float* Zb    = W + off; off += (size_t)25088;
  float* T2    = W + off; off += (size_t)6272 * 192;   // also CRAW
  float* CT    = W + off; off += (size_t)784 * 16;
  float* ST    = W + off; off += (size_t)784 * 16;
  short* XH96  = (short*)(W + off); off += (size_t)25088 * 96 / 2;
  short* XL96  = (short*)(W + off); off += (size_t)25088 * 96 / 2;
  short* XH    = (short*)(W + off); off += (size_t)6272 * 192 / 2;
  short* XL    = (short*)(W + off); off += (size_t)6272 * 192 / 2;
  short* H1H   = (short*)(W + off); off += (size_t)6272 * 576 / 2;
  short* H1L   = (short*)(W + off); off += (size_t)6272 * 576 / 2;
  short* OBH   = (short*)(W + off); off += (size_t)6272 * 192 / 2;
  short* OBL   = (short*)(W + off); off += (size_t)6272 * 192 / 2;
  short* WBH   = (short*)(W + off); off += (size_t)548352 + 16;  // hi arena
  short* WBL   = (short*)(W + off); off += (size_t)548352 + 16;  // lo arena
  const size_t O_c = 0, O_k = 165888, O_q = 193536,
               O_g1 = 211968, O_g2 = 285696, O_qkv = 359424, O_p = 580608,
               O_m1 = 654336, O_m2 = 875520;
  // aliases (group-phase buffers dead in block phase)
  float* CRAW = T2;
  float* Q3 = Kb;
  float* K3 = Kb + (size_t)1204224;
  float* V3 = Vb;

  k_castw<<<4284, 256, 0, stream>>>(convw, kw, vw, qw, gw1, gw2, bqkvw, bprojw,
                                    bmw1, bmw2, WBH, WBL);
  k_rope<<<49, 256, 0, stream>>>(CT, ST);

  // conv (implicit GEMM, K=864, tap-major weights) + LN (emits ln_out-split for it=0 qproj)
  k_mgemm<0, 0><<<dim3(196, 3), 128, 0, stream>>>(x, nullptr, nullptr,
      WBH + O_c, WBL + O_c, nullptr, CRAW, 6272, 192, 864,
      nullptr, nullptr, nullptr, nullptr, nullptr, nullptr, nullptr);
  k_ln_epi<0><<<1568, 256, 0, stream>>>(CRAW, ln_out_g, ln_out_b, ln_out_g, ln_out_b,
                                        XOUT, XH, XL, 6272);

  // LN(x; ln_in) split once; fused K+V projection over adjacent [288][96] weights
  k_lnsplit<96><<<6272, 256, 0, stream>>>(x, ln_in_g, ln_in_b, XH96, XL96, 25088);
  k_mgemm<5, 1><<<dim3(784, 5), 128, 0, stream>>>(nullptr, XH96, XL96,
      WBH + O_k, WBL + O_k, nullptr, nullptr, 25088, 288, 96,
      nullptr, nullptr, Kb, Vb, nullptr, nullptr, nullptr);

  for (int it = 0; it < 3; ++it) {
    // XH/XL hold split(LN(XOUT; ln_out)) from conv ln_epi or previous ln_epi<1>
    k_mgemm<0, 1><<<dim3(196, 2), 128, 0, stream>>>(nullptr, XH, XL,
        WBH + O_q, WBL + O_q, nullptr, Qb, 6272, 96, 192,
        nullptr, nullptr, nullptr, nullptr, nullptr, nullptr, nullptr);
    k_pass1<<<6272, 256, 0, stream>>>(Kb, Qb, rpb, tau, Mb, Zb);
    k_pass2<<<6272, 192, 0, stream>>>(Kb, Qb, Vb, Mb, Zb, rpb, tau, ln_at_g, ln_at_b,
                                      XOUT, XH, XL);  // emits raw-XOUT split for g1
    k_mgemm<1, 1><<<dim3(196, 6), 128, 0, stream>>>(nullptr, XH, XL,
        WBH + O_g1, WBL + O_g1, gb1, nullptr, 6272, 384, 192,
        nullptr, nullptr, nullptr, nullptr, nullptr, H1H, H1L);
    k_mgemm<0, 1><<<dim3(196, 3), 128, 0, stream>>>(nullptr, H1H, H1L,
        WBH + O_g2, WBL + O_g2, gb2, T2, 6272, 192, 384,
        nullptr, nullptr, nullptr, nullptr, nullptr, nullptr, nullptr);
    // emit next consumer's LN split: it<2 -> ln_out (qproj), it==2 -> bln1[0] (qkv)
    const float* eg = (it < 2) ? ln_out_g : bln1g;
    const float* eb = (it < 2) ? ln_out_b : bln1b;
    k_ln_epi<1><<<1568, 256, 0, stream>>>(T2, ln_ml_g, ln_ml_b, eg, eb,
                                          XOUT, XH, XL, 6272);
  }

  for (int i = 0; i < 2; ++i) {
    // XH/XL hold split(LN(XOUT; bln1_i))
    k_mgemm<3, 1><<<dim3(196, 9), 128, 0, stream>>>(nullptr, XH, XL,
        WBH + O_qkv + (size_t)i * 110592, WBL + O_qkv + (size_t)i * 110592, nullptr,
        nullptr, 6272, 576, 192, CT, ST, Q3, K3, V3, nullptr, nullptr);
    k_attn<<<9408, 256, 0, stream>>>(Q3, K3, V3, OBH, OBL);
    k_mgemm<2, 1><<<dim3(196, 3), 128, 0, stream>>>(nullptr, OBH, OBL,
        WBH + O_p + (size_t)i * 36864, WBL + O_p + (size_t)i * 36864,
        bprojb + (size_t)i * 192, XOUT, 6272, 192, 192,
        nullptr, nullptr, nullptr, nullptr, nullptr, nullptr, nullptr);
    k_lnsplit<192><<<1568, 256, 0, stream>>>(XOUT, bln2g + (size_t)i * 192,
        bln2b + (size_t)i * 192, XH, XL, 6272);
    k_mgemm<1, 1><<<dim3(196, 9), 128, 0, stream>>>(nullptr, XH, XL,
        WBH + O_m1 + (size_t)i * 110592, WBL + O_m1 + (size_t)i * 110592,
        bmb1 + (size_t)i * 576, nullptr, 6272, 576, 192,
        nullptr, nullptr, nullptr, nullptr, nullptr, H1H, H1L);
    k_mgemm<2, 1><<<dim3(196, 3), 128, 0, stream>>>(nullptr, H1H, H1L,
        WBH + O_m2 + (size_t)i * 110592, WBL + O_m2 + (size_t)i * 110592,
        bmb2 + (size_t)i * 192, XOUT, 6272, 192, 576,
        nullptr, nullptr, nullptr, nullptr, nullptr, nullptr, nullptr);
    if (i == 0)
      k_lnsplit<192><<<1568, 256, 0, stream>>>(XOUT, bln1g + 192, bln1b + 192,
                                               XH, XL, 6272);
  }
}

// Round 22
// 613.755 us; speedup vs baseline: 1.2110x; 1.0022x over previous
//
#include <hip/hip_runtime.h>
#include <hip/hip_bf16.h>

#define DEV __device__ __forceinline__

typedef __attribute__((ext_vector_type(8))) short short8;
typedef __attribute__((ext_vector_type(4))) float f32x4;

DEV unsigned short f2b(float f) {
  union { float f; unsigned u; } v; v.f = f;
  unsigned r = v.u + 0x7FFFu + ((v.u >> 16) & 1u);  // RNE
  return (unsigned short)(r >> 16);
}
DEV float b2f16(unsigned short b) {
  union { unsigned u; float f; } v; v.u = ((unsigned)b) << 16;
  return v.f;
}
// cheap truncation split: hi+lo carry ~16 mantissa bits (error ~2^-17 rel)
DEV void tsplit(float v, short& h, short& l) {
  union { float f; unsigned u; } c; c.f = v;
  unsigned short hu = (unsigned short)(c.u >> 16);
  union { unsigned u; float f; } hb; hb.u = (unsigned)hu << 16;
  union { float f; unsigned u; } c2; c2.f = v - hb.f;
  h = (short)hu; l = (short)(c2.u >> 16);
}

// ---------------- fused weight cast f32 -> bf16 hi/lo arenas (RNE, one-time) ----------------
// conv weights are stored TAP-MAJOR: dst[co*864 + k9*96 + ci] = src[co*864 + ci*9 + k9]
__global__ void k_castw(const float* __restrict__ s0, const float* __restrict__ s1,
    const float* __restrict__ s2, const float* __restrict__ s3,
    const float* __restrict__ s4, const float* __restrict__ s5,
    const float* __restrict__ s6, const float* __restrict__ s7,
    const float* __restrict__ s8, const float* __restrict__ s9,
    short* __restrict__ dh, short* __restrict__ dl) {
  int idx = blockIdx.x * 256 + threadIdx.x;
  if (idx >= 1096704) return;
  float v;
  if (idx < 165888) {
    int co = idx / 864, rem = idx % 864;
    int k9 = rem / 96, ci = rem % 96;
    v = s0[co * 864 + ci * 9 + k9];
  } else {
    const float* src; int base;
    if      (idx < 175104) { src = s1; base = 165888; }
    else if (idx < 193536) { src = s2; base = 175104; }
    else if (idx < 211968) { src = s3; base = 193536; }
    else if (idx < 285696) { src = s4; base = 211968; }
    else if (idx < 359424) { src = s5; base = 285696; }
    else if (idx < 580608) { src = s6; base = 359424; }
    else if (idx < 654336) { src = s7; base = 580608; }
    else if (idx < 875520) { src = s8; base = 654336; }
    else                   { src = s9; base = 875520; }
    v = src[idx - base];
  }
  unsigned short h = f2b(v);
  dh[idx] = (short)h;
  dl[idx] = (short)f2b(v - b2f16(h));
}

// ---------------- rope tables: ct/st [784][16] ----------------
__global__ void k_rope(float* ct, float* st) {
  int idx = blockIdx.x * 256 + threadIdx.x;
  if (idx >= 784 * 16) return;
  int n = idx >> 4, j = idx & 15;
  float inv = powf(10000.f, -(float)(2 * j) / 32.f);
  float ang = (float)n * inv;
  ct[idx] = cosf(ang);
  st[idx] = sinf(ang);
}

// ---------------- LN + split: xh/xl = split(LN(in; g,b)) ----------------
template<int D>
__global__ __launch_bounds__(256) void k_lnsplit(const float* __restrict__ in,
    const float* __restrict__ g, const float* __restrict__ b,
    short* __restrict__ xh, short* __restrict__ xl, int M) {
  int tok = blockIdx.x * 4 + (threadIdx.x >> 6);
  int l = threadIdx.x & 63;
  if (tok >= M) return;  // wave-uniform
  const float* row = in + (size_t)tok * D;
  constexpr int E = (D + 63) / 64;
  float v[E];
  float s = 0.f, s2 = 0.f;
#pragma unroll
  for (int e = 0; e < E; ++e) {
    int i = e * 64 + l;
    float x = (i < D) ? row[i] : 0.f;
    v[e] = x; s += x; s2 += x * x;
  }
  for (int off = 32; off; off >>= 1) { s += __shfl_xor(s, off); s2 += __shfl_xor(s2, off); }
  float mean = s / D, var = s2 / D - mean * mean;
  float rstd = rsqrtf(var + 1e-5f);
#pragma unroll
  for (int e = 0; e < E; ++e) {
    int i = e * 64 + l;
    if (i < D) {
      float r = (v[e] - mean) * rstd * g[i] + b[i];
      short h2, l2; tsplit(r, h2, l2);
      xh[(size_t)tok * D + i] = h2;
      xl[(size_t)tok * D + i] = l2;
    }
  }
}

// ---------------- LN epilogue D=192: out = (write|add) LN(raw; g,b);
// also emits split(LN(out; eg,eb)) for the next GEMM consumer ----------------
template<int ADD>
__global__ __launch_bounds__(256) void k_ln_epi(const float* __restrict__ raw,
    const float* __restrict__ g, const float* __restrict__ b,
    const float* __restrict__ eg, const float* __restrict__ eb,
    float* __restrict__ out, short* __restrict__ xh, short* __restrict__ xl, int M) {
  int tok = blockIdx.x * 4 + (threadIdx.x >> 6);
  int l = threadIdx.x & 63;
  if (tok >= M) return;
  const float* row = raw + (size_t)tok * 192;
  float v[3];
  float s = 0.f, s2 = 0.f;
#pragma unroll
  for (int e = 0; e < 3; ++e) {
    float x = row[e * 64 + l];
    v[e] = x; s += x; s2 += x * x;
  }
  for (int off = 32; off; off >>= 1) { s += __shfl_xor(s, off); s2 += __shfl_xor(s2, off); }
  float mean = s / 192.f, var = s2 / 192.f - mean * mean;
  float rstd = rsqrtf(var + 1e-5f);
  float* orow = out + (size_t)tok * 192;
  float nv[3];
  float t = 0.f, t2 = 0.f;
#pragma unroll
  for (int e = 0; e < 3; ++e) {
    int i = e * 64 + l;
    float r = (v[e] - mean) * rstd * g[i] + b[i];
    float x = ADD ? (orow[i] + r) : r;
    orow[i] = x;
    nv[e] = x;
    t += x; t2 += x * x;
  }
  for (int off = 32; off; off >>= 1) { t += __shfl_xor(t, off); t2 += __shfl_xor(t2, off); }
  float m2 = t / 192.f, v2 = t2 / 192.f - m2 * m2;
  float rstd2 = rsqrtf(v2 + 1e-5f);
#pragma unroll
  for (int e = 0; e < 3; ++e) {
    int i = e * 64 + l;
    float r = (nv[e] - m2) * rstd2 * eg[i] + eb[i];
    short h2, l2; tsplit(r, h2, l2);
    xh[(size_t)tok * 192 + i] = h2;
    xl[(size_t)tok * 192 + i] = l2;
  }
}

// ---------------- MFMA bf16x2 split GEMM: C = A @ W^T ----------------
// tile 32(M) x 64(N), BK=32, 128 threads = 2 waves; wave w owns N-half.
// acc = ah*bh + ah*bl + al*bh.
// SRC: 0 = conv f32 im2col (tap-major weights), 1 = pre-split bf16 A (AH/AL).
// EPI: 0 store f32 | 1 gelu -> split store to oh/ol | 2 add-into-C
//      | 3 rope-scatter to o1/o2/o3 (qkv) | 5 split K/V store (n<96 -> o1, else o2).
template<int EPI, int SRC>
__global__ __launch_bounds__(128) void k_mgemm(
    const float* __restrict__ Aconv, const short* __restrict__ AH,
    const short* __restrict__ AL, const short* __restrict__ WH,
    const short* __restrict__ WL, const float* __restrict__ bias,
    float* __restrict__ C, int M, int N, int K,
    const float* __restrict__ ct, const float* __restrict__ st,
    float* __restrict__ o1, float* __restrict__ o2, float* __restrict__ o3,
    short* __restrict__ oh, short* __restrict__ ol) {
  __shared__ short AsH[32][40], AsL[32][40];
  __shared__ short BsH[64][40], BsL[64][40];
  int t = threadIdx.x;
  int m0 = blockIdx.x * 32, n0 = blockIdx.y * 64;
  int sr = t >> 2, sq = (t & 3) * 8;       // A stage: row [0,32), k-offset (8/thread)
  int sr2 = t >> 1, sq2 = (t & 1) * 16;    // B stage: row [0,64), k-half (16/thread)
  int lane = t & 63, w = t >> 6;           // wave w in {0,1} -> N-half
  int fr = lane & 15, fq = lane >> 4;      // frag row, k-block
  f32x4 acc[2][2];
#pragma unroll
  for (int i = 0; i < 2; ++i)
#pragma unroll
    for (int j = 0; j < 2; ++j) acc[i][j] = (f32x4){0.f, 0.f, 0.f, 0.f};

  for (int kt = 0; kt < K; kt += 32) {
    // ---- A tile ----
    if (SRC == 1) {
      *(short8*)&AsH[sr][sq] = *(const short8*)&AH[(size_t)(m0 + sr) * K + kt + sq];
      *(short8*)&AsL[sr][sq] = *(const short8*)&AL[(size_t)(m0 + sr) * K + kt + sq];
    } else {
      short8 vh, vl;
      int m = m0 + sr;
      int b = m / 784, rm = m % 784, ho = rm / 28, wo = rm % 28;
      int k = kt + sq;                      // octet never straddles a tap (96 % 8 == 0)
      int k9 = k / 96, ci0 = k % 96;
      int hi = 2 * ho - 1 + k9 / 3, wi = 2 * wo - 1 + k9 % 3;
      if (hi >= 0 && hi < 56 && wi >= 0 && wi < 56) {
        const float* src = &Aconv[((size_t)b * 3136 + hi * 56 + wi) * 96 + ci0];
        float4 a0 = *(const float4*)src;
        float4 a1 = *(const float4*)(src + 4);
        float av[8] = {a0.x, a0.y, a0.z, a0.w, a1.x, a1.y, a1.z, a1.w};
#pragma unroll
        for (int j = 0; j < 8; ++j) { short h, l2; tsplit(av[j], h, l2); vh[j] = h; vl[j] = l2; }
      } else {
#pragma unroll
        for (int j = 0; j < 8; ++j) { vh[j] = 0; vl[j] = 0; }
      }
      *(short8*)&AsH[sr][sq] = vh;
      *(short8*)&AsL[sr][sq] = vl;
    }
    // ---- B tile: row sr2, k-half sq2 ----
    {
      int n = n0 + sr2;
      if (n < N) {
        *(short8*)&BsH[sr2][sq2]     = *(const short8*)&WH[(size_t)n * K + kt + sq2];
        *(short8*)&BsH[sr2][sq2 + 8] = *(const short8*)&WH[(size_t)n * K + kt + sq2 + 8];
        *(short8*)&BsL[sr2][sq2]     = *(const short8*)&WL[(size_t)n * K + kt + sq2];
        *(short8*)&BsL[sr2][sq2 + 8] = *(const short8*)&WL[(size_t)n * K + kt + sq2 + 8];
      } else {
        short8 z = {0, 0, 0, 0, 0, 0, 0, 0};
        *(short8*)&BsH[sr2][sq2] = z; *(short8*)&BsH[sr2][sq2 + 8] = z;
        *(short8*)&BsL[sr2][sq2] = z; *(short8*)&BsL[sr2][sq2 + 8] = z;
      }
    }
    __syncthreads();
    short8 ah[2], al[2], bh[2], bl[2];
#pragma unroll
    for (int s = 0; s < 2; ++s) {
      ah[s] = *(const short8*)&AsH[s * 16 + fr][fq * 8];
      al[s] = *(const short8*)&AsL[s * 16 + fr][fq * 8];
      bh[s] = *(const short8*)&BsH[w * 32 + s * 16 + fr][fq * 8];
      bl[s] = *(const short8*)&BsL[w * 32 + s * 16 + fr][fq * 8];
    }
#pragma unroll
    for (int i = 0; i < 2; ++i)
#pragma unroll
      for (int j = 0; j < 2; ++j) {
        acc[i][j] = __builtin_amdgcn_mfma_f32_16x16x32_bf16(ah[i], bh[j], acc[i][j], 0, 0, 0);
        acc[i][j] = __builtin_amdgcn_mfma_f32_16x16x32_bf16(ah[i], bl[j], acc[i][j], 0, 0, 0);
        acc[i][j] = __builtin_amdgcn_mfma_f32_16x16x32_bf16(al[i], bh[j], acc[i][j], 0, 0, 0);
      }
    __syncthreads();
  }
  // epilogue: C/D layout col = lane&15, row = (lane>>4)*4 + r   [m89]
#pragma unroll
  for (int i = 0; i < 2; ++i) {
#pragma unroll
    for (int j = 0; j < 2; ++j) {
      int n = n0 + w * 32 + j * 16 + fr;
#pragma unroll
      for (int r = 0; r < 4; ++r) {
        int m = m0 + i * 16 + fq * 4 + r;
        float v = acc[i][j][r];
        float pa = 0.f;
        if (EPI == 3) pa = __shfl_xor(v, 1);  // rope partner (n^1 <-> lane^1); all lanes
        if (n >= N) continue;
        if (bias) v += bias[n];
        if (EPI == 1) {
          v = 0.5f * v * (1.f + erff(v * 0.70710678118654752f));
          short h2, l2; tsplit(v, h2, l2);
          oh[(size_t)m * N + n] = h2;
          ol[(size_t)m * N + n] = l2;
        } else if (EPI == 3) {
          int sec = n / 192, d = n % 192, h = d / 32, dh = d % 32;
          int b = m / 784, mm = m % 784;
          float val;
          if (sec < 2) {
            int jj = dh >> 1;
            float cc = ct[mm * 16 + jj], ss = st[mm * 16 + jj];
            val = (dh & 1) ? (v * cc + pa * ss) : (v * cc - pa * ss);
          } else val = v;
          float* dst = (sec == 0) ? o1 : ((sec == 1) ? o2 : o3);
          dst[(((size_t)b * 6 + h) * 784 + mm) * 32 + dh] = val;
        } else if (EPI == 5) {
          if (n < 96) o1[(size_t)m * 96 + n] = v;
          else        o2[(size_t)m * 192 + (n - 96)] = v;
        } else if (EPI == 2) {
          C[(size_t)m * N + n] += v;
        } else {
          C[(size_t)m * N + n] = v;
        }
      }
    }
  }
}

// ---------------- pass1: wave-per-token softmax stats over deduped <=9 neighbors ----------------
__global__ __launch_bounds__(256) void k_pass1(const float* __restrict__ kk,
    const float* __restrict__ q, const float* __restrict__ rpb,
    const float* __restrict__ tau, float* __restrict__ M, float* __restrict__ Z) {
  int tok = blockIdx.x * 4 + (threadIdx.x >> 6);   // [0, 25088)
  int l = threadIdx.x & 63;
  int b = tok / 3136, n = tok % 3136;
  int r = n / 56, c = n % 56, r0 = r >> 1, c0 = c >> 1;
  int oi[9]; bool keep[9];
#pragma unroll
  for (int kki = 0; kki < 9; ++kki) {
    int dr = kki / 3 - 1, dc = kki % 3 - 1;
    int rr = min(max(r0 + dr, 0), 27), cc = min(max(c0 + dc, 0), 27);
    oi[kki] = rr * 28 + cc;
  }
#pragma unroll
  for (int kki = 0; kki < 9; ++kki) {
    bool kp = true;
#pragma unroll
    for (int k2 = kki + 1; k2 < 9; ++k2) if (oi[k2] == oi[kki]) kp = false;
    keep[kki] = kp;
  }
  float scale = expf(tau[0]);
  const float* kr = kk + (size_t)tok * 96;
  float k0 = kr[l];
  float k1 = (l < 32) ? kr[64 + l] : 0.f;
  float lg[9];
  float mx = -1e30f;
#pragma unroll
  for (int kki = 0; kki < 9; ++kki) {
    if (keep[kki]) {
      const float* qr = q + ((size_t)b * 784 + oi[kki]) * 96;
      float part = k0 * qr[l];
      if (l < 32) part += k1 * qr[64 + l];
      for (int off = 32; off; off >>= 1) part += __shfl_xor(part, off);
      lg[kki] = part * scale + rpb[kki];
      mx = fmaxf(mx, lg[kki]);
    } else lg[kki] = -1e30f;
  }
  float z = 0.f;
#pragma unroll
  for (int kki = 0; kki < 9; ++kki) if (keep[kki]) z += expf(lg[kki] - mx);
  if (l == 0) { M[tok] = mx; Z[tok] = z; }
}

// ---------------- pass2: gather, upd, /denom, LN, residual; emits raw-XOUT split ----------------
// XCD-chunked block swizzle: 6272 = 8*784 (T1 locality).
__global__ __launch_bounds__(192) void k_pass2(const float* __restrict__ kk,
    const float* __restrict__ q, const float* __restrict__ vv,
    const float* __restrict__ M, const float* __restrict__ Z,
    const float* __restrict__ rpb, const float* __restrict__ tau,
    const float* __restrict__ g, const float* __restrict__ bb,
    float* __restrict__ xout, short* __restrict__ xh, short* __restrict__ xl) {
  int bid = blockIdx.x;
  int blk = (bid & 7) * 784 + (bid >> 3);   // bijective on [0,6272)
  int b = blk / 784, m = blk % 784;
  int r2 = m / 28, c2 = m % 28;
  int r0lo = (r2 == 0) ? 0 : r2 - 1, r0hi = (r2 == 27) ? 27 : r2 + 1;
  int c0lo = (c2 == 0) ? 0 : c2 - 1, c0hi = (c2 == 27) ? 27 : c2 + 1;
  int nrow = 2 * (r0hi - r0lo + 1), ncol = 2 * (c0hi - c0lo + 1);
  int cnt = nrow * ncol;  // <= 36
  __shared__ float qm[96], p[36];
  __shared__ int nlist[36];
  __shared__ float2 red[192];
  int t = threadIdx.x;
  if (t < 96) qm[t] = q[(size_t)blk * 96 + t];
  __syncthreads();
  if (t < cnt) {
    int rr = 2 * r0lo + t / ncol, cc = 2 * c0lo + t % ncol;
    int n = rr * 56 + cc, rr0 = rr >> 1, cc0 = cc >> 1;
    int kkf = 0;
#pragma unroll
    for (int kki = 0; kki < 9; ++kki) {
      int dr = kki / 3 - 1, dc = kki % 3 - 1;
      int ra = min(max(rr0 + dr, 0), 27), ca = min(max(cc0 + dc, 0), 27);
      if (ra == r2 && ca == c2) kkf = kki;  // last-kk-wins (matches numpy overwrite)
    }
    const float* krow = kk + ((size_t)b * 3136 + n) * 96;
    float d = 0.f;
    for (int i = 0; i < 96; ++i) d += krow[i] * qm[i];
    float scale = expf(tau[0]);
    float lg = d * scale + rpb[kkf];
    size_t idn = (size_t)b * 3136 + n;
    p[t] = expf(lg - M[idn]) / Z[idn];
    nlist[t] = n;
  }
  __syncthreads();
  float denom = 0.f;
  for (int jn = 0; jn < cnt; ++jn) denom += p[jn];
  float acc = 0.f;
  for (int jn = 0; jn < cnt; ++jn)
    acc += p[jn] * vv[((size_t)b * 3136 + nlist[jn]) * 192 + t];
  float upd = acc / (denom + 1e-8f);
  red[t] = make_float2(upd, upd * upd);
  __syncthreads();
  for (int s = 128; s > 0; s >>= 1) {
    if (t < s && t + s < 192) { red[t].x += red[t + s].x; red[t].y += red[t + s].y; }
    __syncthreads();
  }
  float mean = red[0].x / 192.f, var = red[0].y / 192.f - mean * mean;
  float rstd = rsqrtf(var + 1e-5f);
  float nv = xout[(size_t)blk * 192 + t] + (upd - mean) * rstd * g[t] + bb[t];
  xout[(size_t)blk * 192 + t] = nv;
  short h2, l2; tsplit(nv, h2, l2);
  xh[(size_t)blk * 192 + t] = h2;
  xl[(size_t)blk * 192 + t] = l2;
}

// ---------------- neighborhood attention 7x7: V preloaded before softmax ----------------
// All VMEM (8 K float4 + 25 V scalars) issued before the softmax chain; PV is
// pure VALU on cached registers. readlane pair-PV, fused sum, split output.
__global__ __launch_bounds__(256) void k_attn(const float* __restrict__ q3,
    const float* __restrict__ k3, const float* __restrict__ v3,
    short* __restrict__ obh, short* __restrict__ obl) {
  int bid = blockIdx.x;
  int swz = (bid & 7) * 1176 + (bid >> 3);  // bijective on [0,9408)
  int unit = swz * 4 + (threadIdx.x >> 6);
  int l = threadIdx.x & 63;
  int b = unit / (6 * 784), rem = unit % (6 * 784), h = rem / 784, m = rem % 784;
  int i = m / 28, j = m % 28;
  int ib = min(max(i, 3), 24) - 3, jb = min(max(j, 3), 24) - 3;
  size_t base = (size_t)(b * 6 + h) * 784 * 32;
  int half = l >> 5, d = l & 31;
  const float* vb = v3 + base + d;
  int rowbase = ib * 28 + jb;
  // ---- V preload: addresses geometry-only; loads overlap QK + softmax ----
  float vcache[25];
#pragma unroll
  for (int kk2 = 0; kk2 < 25; ++kk2) {
    const int k0c = kk2;
    const int k1c = (kk2 + 25 <= 48) ? kk2 + 25 : 48;
    const int c0 = (k0c / 7) * 28 + (k0c % 7);
    const int c1 = (k1c / 7) * 28 + (k1c % 7);
    int nk = rowbase + (half ? c1 : c0);
    vcache[kk2] = vb[(size_t)nk * 32];
  }
  // ---- QK dot ----
  const float4* q4 = (const float4*)(q3 + base + (size_t)m * 32);
  float4 qv[8];
#pragma unroll
  for (int e = 0; e < 8; ++e) qv[e] = q4[e];
  float logit = -1e30f;
  if (l < 49) {
    int nk = (ib + l / 7) * 28 + (jb + l % 7);
    const float4* k4 = (const float4*)(k3 + base + (size_t)nk * 32);
    float a = 0.f;
#pragma unroll
    for (int e = 0; e < 8; ++e) {
      float4 kv = k4[e];
      a += qv[e].x * kv.x + qv[e].y * kv.y + qv[e].z * kv.z + qv[e].w * kv.w;
    }
    logit = a * 0.17677669529663687f;  // 32^-0.5
  }
  float mx = logit;
  for (int off = 32; off; off >>= 1) mx = fmaxf(mx, __shfl_xor(mx, off));
  float p = (l < 49) ? expf(logit - mx) : 0.f;
  // ---- PV: pure VALU on cached V ----
  float accA = 0.f, accB = 0.f, psum = 0.f;
  int pbits = __float_as_int(p);
#pragma unroll
  for (int kk2 = 0; kk2 < 25; ++kk2) {
    const int k0c = kk2;
    const int k1c = (kk2 + 25 <= 48) ? kk2 + 25 : 48;
    float pk0 = __int_as_float(__builtin_amdgcn_readlane(pbits, k0c));
    float pk1 = (kk2 < 24) ? __int_as_float(__builtin_amdgcn_readlane(pbits, k1c)) : 0.f;
    float pk = half ? pk1 : pk0;
    psum += pk;
    float term = pk * vcache[kk2];
    if (kk2 & 1) accB += term; else accA += term;
  }
  float acc = accA + accB;
  acc += __shfl_xor(acc, 32);
  psum += __shfl_xor(psum, 32);
  if (l < 32) {
    float o = acc / psum;
    short h2, l2; tsplit(o, h2, l2);
    size_t idx = (((size_t)b * 784 + m) * 6 + h) * 32 + l;
    obh[idx] = h2;
    obl[idx] = l2;
  }
}

extern "C" void kernel_launch(void* const* d_in, const int* in_sizes, int n_in,
                              void* d_out, int out_size, void* d_ws, size_t ws_size,
                              hipStream_t stream) {
  (void)in_sizes; (void)n_in; (void)out_size; (void)ws_size;
  const float* x        = (const float*)d_in[0];
  const float* convw    = (const float*)d_in[1];
  const float* qw       = (const float*)d_in[2];
  const float* kw       = (const float*)d_in[3];
  const float* vw       = (const float*)d_in[4];
  const float* ln_in_g  = (const float*)d_in[5];
  const float* ln_in_b  = (const float*)d_in[6];
  const float* ln_out_g = (const float*)d_in[7];
  const float* ln_out_b = (const float*)d_in[8];
  const float* ln_at_g  = (const float*)d_in[9];
  const float* ln_at_b  = (const float*)d_in[10];
  const float* ln_ml_g  = (const float*)d_in[11];
  const float* ln_ml_b  = (const float*)d_in[12];
  const float* gw1      = (const float*)d_in[13];
  const float* gb1      = (const float*)d_in[14];
  const float* gw2      = (const float*)d_in[15];
  const float* gb2      = (const float*)d_in[16];
  const float* tau      = (const float*)d_in[17];
  const float* rpb      = (const float*)d_in[18];
  const float* bln1g    = (const float*)d_in[19];
  const float* bln1b    = (const float*)d_in[20];
  const float* bln2g    = (const float*)d_in[21];
  const float* bln2b    = (const float*)d_in[22];
  const float* bqkvw    = (const float*)d_in[23];
  const float* bprojw   = (const float*)d_in[24];
  const float* bprojb   = (const float*)d_in[25];
  const float* bmw1     = (const float*)d_in[26];
  const float* bmb1     = (const float*)d_in[27];
  const float* bmw2     = (const float*)d_in[28];
  const float* bmb2     = (const float*)d_in[29];

  float* XOUT = (float*)d_out;  // residual stream lives in d_out (f32, 8*784*192)

  float* W = (float*)d_ws;
  size_t off = 0;
  float* Kb    = W + off; off += (size_t)25088 * 96;
  float* Vb    = W + off; off += (size_t)25088 * 192;
  float* Qb    = W + off; off += (size_t)6272 * 96;
  float* Mb    = W + off; off += (size_t)25088;
  float* Zb    = W + off; off += (size_t)25088;
  float* T2    = W + off; off += (size_t)6272 * 192;   // also CRAW
  float* CT    = W + off; off += (size_t)784 * 16;
  float* ST    = W + off; off += (size_t)784 * 16;
  short* XH96  = (short*)(W + off); off += (size_t)25088 * 96 / 2;
  short* XL96  = (short*)(W + off); off += (size_t)25088 * 96 / 2;
  short* XH    = (short*)(W + off); off += (size_t)6272 * 192 / 2;
  short* XL    = (short*)(W + off); off += (size_t)6272 * 192 / 2;
  short* H1H   = (short*)(W + off); off += (size_t)6272 * 576 / 2;
  short* H1L   = (short*)(W + off); off += (size_t)6272 * 576 / 2;
  short* OBH   = (short*)(W + off); off += (size_t)6272 * 192 / 2;
  short* OBL   = (short*)(W + off); off += (size_t)6272 * 192 / 2;
  short* WBH   = (short*)(W + off); off += (size_t)548352 + 16;  // hi arena
  short* WBL   = (short*)(W + off); off += (size_t)548352 + 16;  // lo arena
  const size_t O_c = 0, O_k = 165888, O_q = 193536,
               O_g1 = 211968, O_g2 = 285696, O_qkv = 359424, O_p = 580608,
               O_m1 = 654336, O_m2 = 875520;
  // aliases (group-phase buffers dead in block phase)
  float* CRAW = T2;
  float* Q3 = Kb;
  float* K3 = Kb + (size_t)1204224;
  float* V3 = Vb;

  k_castw<<<4284, 256, 0, stream>>>(convw, kw, vw, qw, gw1, gw2, bqkvw, bprojw,
                                    bmw1, bmw2, WBH, WBL);
  k_rope<<<49, 256, 0, stream>>>(CT, ST);

  // conv (implicit GEMM, K=864, tap-major weights) + LN (emits ln_out-split for it=0 qproj)
  k_mgemm<0, 0><<<dim3(196, 3), 128, 0, stream>>>(x, nullptr, nullptr,
      WBH + O_c, WBL + O_c, nullptr, CRAW, 6272, 192, 864,
      nullptr, nullptr, nullptr, nullptr, nullptr, nullptr, nullptr);
  k_ln_epi<0><<<1568, 256, 0, stream>>>(CRAW, ln_out_g, ln_out_b, ln_out_g, ln_out_b,
                                        XOUT, XH, XL, 6272);

  // LN(x; ln_in) split once; fused K+V projection over adjacent [288][96] weights
  k_lnsplit<96><<<6272, 256, 0, stream>>>(x, ln_in_g, ln_in_b, XH96, XL96, 25088);
  k_mgemm<5, 1><<<dim3(784, 5), 128, 0, stream>>>(nullptr, XH96, XL96,
      WBH + O_k, WBL + O_k, nullptr, nullptr, 25088, 288, 96,
      nullptr, nullptr, Kb, Vb, nullptr, nullptr, nullptr);

  for (int it = 0; it < 3; ++it) {
    // XH/XL hold split(LN(XOUT; ln_out)) from conv ln_epi or previous ln_epi<1>
    k_mgemm<0, 1><<<dim3(196, 2), 128, 0, stream>>>(nullptr, XH, XL,
        WBH + O_q, WBL + O_q, nullptr, Qb, 6272, 96, 192,
        nullptr, nullptr, nullptr, nullptr, nullptr, nullptr, nullptr);
    k_pass1<<<6272, 256, 0, stream>>>(Kb, Qb, rpb, tau, Mb, Zb);
    k_pass2<<<6272, 192, 0, stream>>>(Kb, Qb, Vb, Mb, Zb, rpb, tau, ln_at_g, ln_at_b,
                                      XOUT, XH, XL);  // emits raw-XOUT split for g1
    k_mgemm<1, 1><<<dim3(196, 6), 128, 0, stream>>>(nullptr, XH, XL,
        WBH + O_g1, WBL + O_g1, gb1, nullptr, 6272, 384, 192,
        nullptr, nullptr, nullptr, nullptr, nullptr, H1H, H1L);
    k_mgemm<0, 1><<<dim3(196, 3), 128, 0, stream>>>(nullptr, H1H, H1L,
        WBH + O_g2, WBL + O_g2, gb2, T2, 6272, 192, 384,
        nullptr, nullptr, nullptr, nullptr, nullptr, nullptr, nullptr);
    // emit next consumer's LN split: it<2 -> ln_out (qproj), it==2 -> bln1[0] (qkv)
    const float* eg = (it < 2) ? ln_out_g : bln1g;
    const float* eb = (it < 2) ? ln_out_b : bln1b;
    k_ln_epi<1><<<1568, 256, 0, stream>>>(T2, ln_ml_g, ln_ml_b, eg, eb,
                                          XOUT, XH, XL, 6272);
  }

  for (int i = 0; i < 2; ++i) {
    // XH/XL hold split(LN(XOUT; bln1_i))
    k_mgemm<3, 1><<<dim3(196, 9), 128, 0, stream>>>(nullptr, XH, XL,
        WBH + O_qkv + (size_t)i * 110592, WBL + O_qkv + (size_t)i * 110592, nullptr,
        nullptr, 6272, 576, 192, CT, ST, Q3, K3, V3, nullptr, nullptr);
    k_attn<<<9408, 256, 0, stream>>>(Q3, K3, V3, OBH, OBL);
    k_mgemm<2, 1><<<dim3(196, 3), 128, 0, stream>>>(nullptr, OBH, OBL,
        WBH + O_p + (size_t)i * 36864, WBL + O_p + (size_t)i * 36864,
        bprojb + (size_t)i * 192, XOUT, 6272, 192, 192,
        nullptr, nullptr, nullptr, nullptr, nullptr, nullptr, nullptr);
    k_lnsplit<192><<<1568, 256, 0, stream>>>(XOUT, bln2g + (size_t)i * 192,
        bln2b + (size_t)i * 192, XH, XL, 6272);
    k_mgemm<1, 1><<<dim3(196, 9), 128, 0, stream>>>(nullptr, XH, XL,
        WBH + O_m1 + (size_t)i * 110592, WBL + O_m1 + (size_t)i * 110592,
        bmb1 + (size_t)i * 576, nullptr, 6272, 576, 192,
        nullptr, nullptr, nullptr, nullptr, nullptr, H1H, H1L);
    k_mgemm<2, 1><<<dim3(196, 3), 128, 0, stream>>>(nullptr, H1H, H1L,
        WBH + O_m2 + (size_t)i * 110592, WBL + O_m2 + (size_t)i * 110592,
        bmb2 + (size_t)i * 192, XOUT, 6272, 192, 576,
        nullptr, nullptr, nullptr, nullptr, nullptr, nullptr, nullptr);
    if (i == 0)
      k_lnsplit<192><<<1568, 256, 0, stream>>>(XOUT, bln1g + 192, bln1b + 192,
                                               XH, XL, 6272);
  }
}